// Round 1
// baseline (6286.542 us; speedup 1.0000x reference)
//
#include <hip/hip_runtime.h>
#include <math.h>

// pool_cross on MI355X — round 1: correct fp32 baseline.
//
// Algebraic simplification: bottom_pool(top_pool(a)) == broadcast of
// max-over-H (column max); right_pool(left_pool(a)) == broadcast of
// max-over-W (row max). Therefore the merge-conv input is
//   M[b,c,y,x] = colmax1[b,c,x] + rowmax2[b,c,y]
// and conv3x3(M) decomposes into two 1-D convs over the 128-vectors with
// 3 boundary weight-sum classes each (U indexed by y-class, V by x-class).
// a1/a2/pool1/pool2 are never materialized.

constexpr int NB   = 4;    // batch
constexpr int CDIM = 256;
constexpr int CMID = 128;
constexpr int HS   = 128;
constexpr int WS   = 128;
constexpr float EPS = 1e-5f;

// ---------------------------------------------------------------------------
// K1: conv3x3 (CDIM->CMID) + BN + ReLU + column max (max over y).
// Block: 32-col strip x full 128 rows, 2 output channels. 256 threads.
// thread t: x = t&31, 16 rows starting at (t>>5)*16.
__global__ __launch_bounds__(256) void k_conv_colmax(
    const float* __restrict__ xin, const float* __restrict__ wgt,
    const float* __restrict__ gg, const float* __restrict__ bb,
    const float* __restrict__ mm, const float* __restrict__ vv,
    float* __restrict__ colmax)
{
    const int x0  = blockIdx.x * 32;
    const int co0 = blockIdx.y * 2;
    const int b   = blockIdx.z;
    __shared__ float tile[130 * 34];   // rows gy=-1..128, cols gx=x0-1..x0+32
    __shared__ float red[8][32];
    const int t  = threadIdx.x;
    const int xl = t & 31;
    const int yg = t >> 5;
    const int yb = yg * 16;

    float acc[2][16];
#pragma unroll
    for (int c = 0; c < 2; ++c)
#pragma unroll
        for (int i = 0; i < 16; ++i) acc[c][i] = 0.f;

    for (int ci = 0; ci < CDIM; ++ci) {
        const float* src = xin + (b * CDIM + ci) * (HS * WS);
        for (int idx = t; idx < 130 * 34; idx += 256) {
            int r = idx / 34, c = idx - r * 34;
            int gy = r - 1, gx = x0 + c - 1;
            float v = 0.f;
            if ((unsigned)gy < (unsigned)HS && (unsigned)gx < (unsigned)WS)
                v = src[gy * WS + gx];
            tile[idx] = v;
        }
        __syncthreads();
        float w[2][9];
#pragma unroll
        for (int c = 0; c < 2; ++c) {
            const float* wp = wgt + ((co0 + c) * CDIM + ci) * 9;
#pragma unroll
            for (int k = 0; k < 9; ++k) w[c][k] = wp[k];
        }
        // slide 18 rows; tile row (yb+r) feeds outputs i = r-2..r (ky = r-i)
#pragma unroll
        for (int r = 0; r < 18; ++r) {
            float v0 = tile[(yb + r) * 34 + xl + 0];
            float v1 = tile[(yb + r) * 34 + xl + 1];
            float v2 = tile[(yb + r) * 34 + xl + 2];
#pragma unroll
            for (int ky = 0; ky < 3; ++ky) {
                int i = r - ky;
                if (i >= 0 && i < 16) {
                    acc[0][i] += w[0][ky*3+0]*v0 + w[0][ky*3+1]*v1 + w[0][ky*3+2]*v2;
                    acc[1][i] += w[1][ky*3+0]*v0 + w[1][ky*3+1]*v1 + w[1][ky*3+2]*v2;
                }
            }
        }
        __syncthreads();
    }

#pragma unroll
    for (int c = 0; c < 2; ++c) {
        int co = co0 + c;
        float inv = rsqrtf(vv[co] + EPS);
        float sc = gg[co] * inv;
        float sh = bb[co] - mm[co] * sc;
        float m = 0.f;   // relu output >= 0, so 0 is a safe identity
#pragma unroll
        for (int i = 0; i < 16; ++i)
            m = fmaxf(m, fmaxf(acc[c][i] * sc + sh, 0.f));
        __syncthreads();
        red[yg][xl] = m;
        __syncthreads();
        if (t < 32) {
            float mr = red[0][t];
#pragma unroll
            for (int g2 = 1; g2 < 8; ++g2) mr = fmaxf(mr, red[g2][t]);
            colmax[(b * CMID + co) * WS + x0 + t] = mr;
        }
    }
}

// ---------------------------------------------------------------------------
// K2: conv3x3 (CDIM->CMID) + BN + ReLU + row max (max over x).
// Block: 32-row strip x full 128 cols, 2 output channels.
// thread t: y = t&31, 16 cols starting at (t>>5)*16. LDS stride 131 keeps
// the 32 distinct rows on 32 distinct banks (131*y mod 32 = 3y, 3 coprime 32).
__global__ __launch_bounds__(256) void k_conv_rowmax(
    const float* __restrict__ xin, const float* __restrict__ wgt,
    const float* __restrict__ gg, const float* __restrict__ bb,
    const float* __restrict__ mm, const float* __restrict__ vv,
    float* __restrict__ rowmax)
{
    const int y0  = blockIdx.x * 32;
    const int co0 = blockIdx.y * 2;
    const int b   = blockIdx.z;
    __shared__ float tile[34 * 131];   // rows gy=y0-1..y0+32, cols gx=-1..128
    __shared__ float red[32][8];
    const int t  = threadIdx.x;
    const int yl = t & 31;
    const int xg = t >> 5;
    const int xb = xg * 16;

    float acc[2][16];
#pragma unroll
    for (int c = 0; c < 2; ++c)
#pragma unroll
        for (int i = 0; i < 16; ++i) acc[c][i] = 0.f;

    for (int ci = 0; ci < CDIM; ++ci) {
        const float* src = xin + (b * CDIM + ci) * (HS * WS);
        for (int idx = t; idx < 34 * 130; idx += 256) {
            int r = idx / 130, c = idx - r * 130;
            int gy = y0 + r - 1, gx = c - 1;
            float v = 0.f;
            if ((unsigned)gy < (unsigned)HS && (unsigned)gx < (unsigned)WS)
                v = src[gy * WS + gx];
            tile[r * 131 + c] = v;
        }
        __syncthreads();
        float w[2][9];
#pragma unroll
        for (int c = 0; c < 2; ++c) {
            const float* wp = wgt + ((co0 + c) * CDIM + ci) * 9;
#pragma unroll
            for (int k = 0; k < 9; ++k) w[c][k] = wp[k];
        }
        // slide 18 cols; tile col (xb+c) feeds outputs j = c-2..c (kx = c-j)
#pragma unroll
        for (int c = 0; c < 18; ++c) {
            float v0 = tile[(yl + 0) * 131 + xb + c];
            float v1 = tile[(yl + 1) * 131 + xb + c];
            float v2 = tile[(yl + 2) * 131 + xb + c];
#pragma unroll
            for (int kx = 0; kx < 3; ++kx) {
                int j = c - kx;
                if (j >= 0 && j < 16) {
                    acc[0][j] += w[0][0*3+kx]*v0 + w[0][1*3+kx]*v1 + w[0][2*3+kx]*v2;
                    acc[1][j] += w[1][0*3+kx]*v0 + w[1][1*3+kx]*v1 + w[1][2*3+kx]*v2;
                }
            }
        }
        __syncthreads();
    }

#pragma unroll
    for (int c = 0; c < 2; ++c) {
        int co = co0 + c;
        float inv = rsqrtf(vv[co] + EPS);
        float sc = gg[co] * inv;
        float sh = bb[co] - mm[co] * sc;
        float m = 0.f;
#pragma unroll
        for (int j = 0; j < 16; ++j)
            m = fmaxf(m, fmaxf(acc[c][j] * sc + sh, 0.f));
        __syncthreads();
        red[yl][xg] = m;
        __syncthreads();
        if (t < 32) {
            float mr = red[t][0];
#pragma unroll
            for (int g2 = 1; g2 < 8; ++g2) mr = fmaxf(mr, red[t][g2]);
            rowmax[(b * CMID + co) * HS + y0 + t] = mr;
        }
    }
}

// ---------------------------------------------------------------------------
// K3: 1-D decomposition of the merge conv.
// mode 0: U[r][b][co][x] = sum_ci sum_kx (sum_{ky in rowclass r} w[ky][kx]) * colmax[b,ci,x+kx-1]
// mode 1: V[c][b][co][y] = sum_ci sum_ky (sum_{kx in colclass c} w[ky][kx]) * rowmax[b,ci,y+ky-1]
// class 0 = boundary at 0 (drop tap 0), 1 = interior, 2 = boundary at 127 (drop tap 2)
__global__ __launch_bounds__(128) void k_uv(
    const float* __restrict__ pw, const float* __restrict__ cm,
    const float* __restrict__ rm, float* __restrict__ U, float* __restrict__ V)
{
    const int co   = blockIdx.x;
    const int b    = blockIdx.y;
    const int mode = blockIdx.z;
    const int p    = threadIdx.x;
    float acc0 = 0.f, acc1 = 0.f, acc2 = 0.f;
    const float* base = (mode == 0) ? cm : rm;
    for (int ci = 0; ci < CMID; ++ci) {
        const float* w9 = pw + (co * CMID + ci) * 9;
        float s0[3], s1[3], s2[3];
        if (mode == 0) {
#pragma unroll
            for (int k = 0; k < 3; ++k) {
                float a = w9[k], q = w9[3 + k], r = w9[6 + k];
                s0[k] = q + r; s1[k] = a + q + r; s2[k] = a + q;
            }
        } else {
#pragma unroll
            for (int k = 0; k < 3; ++k) {
                float a = w9[k*3 + 0], q = w9[k*3 + 1], r = w9[k*3 + 2];
                s0[k] = q + r; s1[k] = a + q + r; s2[k] = a + q;
            }
        }
        const float* v = base + (b * CMID + ci) * 128;
#pragma unroll
        for (int k = 0; k < 3; ++k) {
            int pos = p + k - 1;
            if ((unsigned)pos < 128u) {
                float vv = v[pos];
                acc0 += s0[k] * vv; acc1 += s1[k] * vv; acc2 += s2[k] * vv;
            }
        }
    }
    float* dst = (mode == 0) ? U : V;
    dst[((0 * NB + b) * CDIM + co) * 128 + p] = acc0;
    dst[((1 * NB + b) * CDIM + co) * 128 + p] = acc1;
    dst[((2 * NB + b) * CDIM + co) * 128 + p] = acc2;
}

// ---------------------------------------------------------------------------
// K4: R = relu( psc*(U+V) + psh  +  csc*conv1x1(x) + csh )
// 1x1 conv as tiled GEMM: 64 co x 64 px per block, 256 threads, 16 acc each.
__global__ __launch_bounds__(256) void k_merge(
    const float* __restrict__ xin, const float* __restrict__ c1w,
    const float* __restrict__ U, const float* __restrict__ V,
    const float* __restrict__ pg, const float* __restrict__ pb,
    const float* __restrict__ pm, const float* __restrict__ pv,
    const float* __restrict__ cg, const float* __restrict__ cb,
    const float* __restrict__ cmn, const float* __restrict__ cv,
    float* __restrict__ R)
{
    const int pt  = blockIdx.x;
    const int co0 = blockIdx.y * 64;
    const int b   = blockIdx.z;
    const int p0  = pt * 64;        // 64 consecutive pixels -> single y row
    const int y   = p0 >> 7;
    const int yc  = (y == 0) ? 0 : ((y == HS - 1) ? 2 : 1);
    __shared__ float Xs[8][64];
    __shared__ float Wsh[8][64];
    const int t   = threadIdx.x;
    const int px0 = (t & 15) * 4;
    const int cl0 = (t >> 4) * 4;
    float acc[4][4];   // [co][px]
#pragma unroll
    for (int i = 0; i < 4; ++i)
#pragma unroll
        for (int j = 0; j < 4; ++j) acc[i][j] = 0.f;

    for (int c0 = 0; c0 < CDIM; c0 += 8) {
#pragma unroll
        for (int it = 0; it < 2; ++it) {
            int idx = t + it * 256;
            int cil = idx >> 6, pp = idx & 63;
            Xs[cil][pp] = xin[(b * CDIM + c0 + cil) * (HS * WS) + p0 + pp];
        }
#pragma unroll
        for (int it = 0; it < 2; ++it) {
            int idx = t + it * 256;
            int cwl = idx >> 3, cil = idx & 7;
            Wsh[cil][cwl] = c1w[(co0 + cwl) * CDIM + c0 + cil];
        }
        __syncthreads();
#pragma unroll
        for (int ci = 0; ci < 8; ++ci) {
            float xr[4], wr[4];
#pragma unroll
            for (int j = 0; j < 4; ++j) xr[j] = Xs[ci][px0 + j];
#pragma unroll
            for (int i = 0; i < 4; ++i) wr[i] = Wsh[ci][cl0 + i];
#pragma unroll
            for (int i = 0; i < 4; ++i)
#pragma unroll
                for (int j = 0; j < 4; ++j) acc[i][j] += wr[i] * xr[j];
        }
        __syncthreads();
    }

#pragma unroll
    for (int i = 0; i < 4; ++i) {
        int co = co0 + cl0 + i;
        float iv  = rsqrtf(pv[co] + EPS);
        float psc = pg[co] * iv;
        float psh = pb[co] - pm[co] * psc;
        float iv2 = rsqrtf(cv[co] + EPS);
        float csc = cg[co] * iv2;
        float csh = cb[co] - cmn[co] * csc;
        const float* Urow = U + ((yc * NB + b) * CDIM + co) * 128;
        const float* Vco  = V + ((0 * NB + b) * CDIM + co) * 128;  // class stride NB*CDIM*128
        float vmid = Vco[(1 * NB) * CDIM * 128 + y];
#pragma unroll
        for (int j = 0; j < 4; ++j) {
            int px = p0 + px0 + j;
            int xx = px & (WS - 1);
            float vterm;
            if (xx == 0)            vterm = Vco[y];
            else if (xx == WS - 1)  vterm = Vco[(2 * NB) * CDIM * 128 + y];
            else                    vterm = vmid;
            float pconv = Urow[xx] + vterm;
            float val = pconv * psc + psh + acc[i][j] * csc + csh;
            R[(b * CDIM + co) * (HS * WS) + px] = fmaxf(val, 0.f);
        }
    }
}

// ---------------------------------------------------------------------------
// K5: final conv3x3 (CDIM->CDIM) + BN + ReLU -> d_out.
// Block: 32x32 spatial tile, 4 output channels. 256 threads, 4 rows each.
__global__ __launch_bounds__(256) void k_final(
    const float* __restrict__ R, const float* __restrict__ w2,
    const float* __restrict__ gg, const float* __restrict__ bb,
    const float* __restrict__ mm, const float* __restrict__ vv,
    float* __restrict__ outp)
{
    const int tile_i = blockIdx.x;
    const int ty = (tile_i >> 2) * 32, tx = (tile_i & 3) * 32;
    const int co0 = blockIdx.y * 4;
    const int b   = blockIdx.z;
    __shared__ float ts[34 * 34];
    const int t  = threadIdx.x;
    const int xl = t & 31;
    const int yg = t >> 5;
    const int yb = yg * 4;
    float acc[4][4];   // [co][row]
#pragma unroll
    for (int c = 0; c < 4; ++c)
#pragma unroll
        for (int i = 0; i < 4; ++i) acc[c][i] = 0.f;

    for (int ci = 0; ci < CDIM; ++ci) {
        const float* src = R + (b * CDIM + ci) * (HS * WS);
        for (int idx = t; idx < 34 * 34; idx += 256) {
            int r = idx / 34, c = idx - r * 34;
            int gy = ty + r - 1, gx = tx + c - 1;
            float v = 0.f;
            if ((unsigned)gy < (unsigned)HS && (unsigned)gx < (unsigned)WS)
                v = src[gy * WS + gx];
            ts[idx] = v;
        }
        __syncthreads();
        float w[4][9];
#pragma unroll
        for (int c = 0; c < 4; ++c) {
            const float* wp = w2 + ((co0 + c) * CDIM + ci) * 9;
#pragma unroll
            for (int k = 0; k < 9; ++k) w[c][k] = wp[k];
        }
#pragma unroll
        for (int r = 0; r < 6; ++r) {
            float v0 = ts[(yb + r) * 34 + xl + 0];
            float v1 = ts[(yb + r) * 34 + xl + 1];
            float v2 = ts[(yb + r) * 34 + xl + 2];
#pragma unroll
            for (int ky = 0; ky < 3; ++ky) {
                int i = r - ky;
                if (i >= 0 && i < 4) {
#pragma unroll
                    for (int c = 0; c < 4; ++c)
                        acc[c][i] += w[c][ky*3+0]*v0 + w[c][ky*3+1]*v1 + w[c][ky*3+2]*v2;
                }
            }
        }
        __syncthreads();
    }

#pragma unroll
    for (int c = 0; c < 4; ++c) {
        int co = co0 + c;
        float inv = rsqrtf(vv[co] + EPS);
        float sc = gg[co] * inv;
        float sh = bb[co] - mm[co] * sc;
#pragma unroll
        for (int i = 0; i < 4; ++i) {
            int yy = ty + yb + i;
            outp[((b * CDIM + co) * HS + yy) * WS + tx + xl] =
                fmaxf(acc[c][i] * sc + sh, 0.f);
        }
    }
}

// ---------------------------------------------------------------------------
extern "C" void kernel_launch(void* const* d_in, const int* in_sizes, int n_in,
                              void* d_out, int out_size, void* d_ws, size_t ws_size,
                              hipStream_t stream)
{
    (void)in_sizes; (void)n_in; (void)out_size; (void)ws_size;
    const float* x    = (const float*)d_in[0];
    const float* p1_w = (const float*)d_in[1];
    const float* p1_g = (const float*)d_in[2];
    const float* p1_b = (const float*)d_in[3];
    const float* p1_m = (const float*)d_in[4];
    const float* p1_v = (const float*)d_in[5];
    const float* p2_w = (const float*)d_in[6];
    const float* p2_g = (const float*)d_in[7];
    const float* p2_b = (const float*)d_in[8];
    const float* p2_m = (const float*)d_in[9];
    const float* p2_v = (const float*)d_in[10];
    const float* p_w  = (const float*)d_in[11];
    const float* p_g  = (const float*)d_in[12];
    const float* p_b  = (const float*)d_in[13];
    const float* p_m  = (const float*)d_in[14];
    const float* p_v  = (const float*)d_in[15];
    const float* c1_w = (const float*)d_in[16];
    const float* c1_g = (const float*)d_in[17];
    const float* c1_b = (const float*)d_in[18];
    const float* c1_m = (const float*)d_in[19];
    const float* c1_v = (const float*)d_in[20];
    const float* c2_w = (const float*)d_in[21];
    const float* c2_g = (const float*)d_in[22];
    const float* c2_b = (const float*)d_in[23];
    const float* c2_m = (const float*)d_in[24];
    const float* c2_v = (const float*)d_in[25];
    float* out = (float*)d_out;
    float* ws  = (float*)d_ws;

    // ws layout (floats): colmax 64K | rowmax 64K | U 384K | V 384K | R 16M
    // total ~70.8 MB
    float* colmax1 = ws;
    float* rowmax2 = ws + 65536;
    float* Ubuf    = ws + 131072;
    float* Vbuf    = ws + 524288;
    float* Rbuf    = ws + 917504;

    k_conv_colmax<<<dim3(4, 64, 4), 256, 0, stream>>>(
        x, p1_w, p1_g, p1_b, p1_m, p1_v, colmax1);
    k_conv_rowmax<<<dim3(4, 64, 4), 256, 0, stream>>>(
        x, p2_w, p2_g, p2_b, p2_m, p2_v, rowmax2);
    k_uv<<<dim3(256, 4, 2), 128, 0, stream>>>(
        p_w, colmax1, rowmax2, Ubuf, Vbuf);
    k_merge<<<dim3(256, 4, 4), 256, 0, stream>>>(
        x, c1_w, Ubuf, Vbuf, p_g, p_b, p_m, p_v,
        c1_g, c1_b, c1_m, c1_v, Rbuf);
    k_final<<<dim3(16, 64, 4), 256, 0, stream>>>(
        Rbuf, c2_w, c2_g, c2_b, c2_m, c2_v, out);
}

// Round 2
// 1050.960 us; speedup vs baseline: 5.9817x; 5.9817x over previous
//
#include <hip/hip_runtime.h>
#include <hip/hip_bf16.h>
#include <math.h>

// pool_cross on MI355X — round 2: MFMA implicit-GEMM convs (bf16 in, fp32 acc).
//
// Structure:
//   memset Xp; k_xprep: x fp32 NCHW -> Xp bf16 padded channel-last [b][130][132][256]
//   k_wprep: conv weights -> Aw bf16 [co][K=2304], K tap-major (k = tap*256+ci)
//   k_conv3_mfma (K1,K2): conv3x3+BN+relu -> O1/O2 bf16 NCHW row slabs
//   k_wprep Aw5 (into dead Xp region)
//   k_reduce: O1 -> colmax (max over y), O2 -> rowmax (max over x)
//   memset regionA (zeros Rp incl. borders; O1/O2/Aw1/Aw2 dead)
//   k_uv: 1-D decomposition of merge conv (pool1+pool2 is rank-1: colmax+rowmax)
//   k_merge: 1x1-conv GEMM + BN + U+V merge + BN + relu -> Rp bf16 padded CL
//   k_conv3_mfma (K5): conv3x3+BN+relu on Rp -> d_out fp32 NCHW

constexpr int NB   = 4;
constexpr int CDIM = 256;
constexpr int CMID = 128;
constexpr int HS   = 128;
constexpr int WS   = 128;
constexpr float EPS = 1e-5f;

typedef __bf16 bf16x8 __attribute__((ext_vector_type(8)));
typedef float  f32x4  __attribute__((ext_vector_type(4)));

// ---------------------------------------------------------------------------
// P0: transpose x[b][ci][y][x] fp32 -> Xp[b][y+1][x+1][ci] bf16 (borders pre-zeroed)
__global__ __launch_bounds__(256) void k_xprep(const float* __restrict__ xin,
                                               __hip_bfloat16* __restrict__ Xp)
{
    const int y = blockIdx.x;
    const int b = blockIdx.y;
    const int t = threadIdx.x;
    __shared__ __hip_bfloat16 lds[128 * 66];   // [xx][ci_l], stride 66 kills conflicts
    for (int c0 = 0; c0 < CDIM; c0 += 64) {
#pragma unroll
        for (int k = 0; k < 32; ++k) {
            int idx = t + k * 256;             // 0..8191
            int ci = idx >> 7;                 // 0..63
            int xx = idx & 127;
            float v = xin[(((size_t)b * CDIM + c0 + ci) * HS + y) * WS + xx];
            lds[xx * 66 + ci] = __float2bfloat16(v);
        }
        __syncthreads();
#pragma unroll
        for (int k = 0; k < 32; ++k) {
            int idx = t + k * 256;
            int ci = idx & 63;
            int xx = idx >> 6;
            Xp[((size_t)((b * 130 + y + 1) * 132) + xx + 1) * 256 + c0 + ci] =
                lds[xx * 66 + ci];
        }
        __syncthreads();
    }
}

// ---------------------------------------------------------------------------
// PW: W[co][ci][3][3] fp32 -> Aw[co][tap*256+ci] bf16
__global__ __launch_bounds__(256) void k_wprep(const float* __restrict__ W,
                                               __hip_bfloat16* __restrict__ Aw)
{
    const int co = blockIdx.x;
    const int t  = threadIdx.x;   // ci
#pragma unroll
    for (int tap = 0; tap < 9; ++tap)
        Aw[(size_t)co * 2304 + tap * 256 + t] =
            __float2bfloat16(W[((size_t)co * CDIM + t) * 9 + tap]);
}

// ---------------------------------------------------------------------------
// Core: conv3x3 (256ci -> 128co tile) + BN + relu via mfma_f32_16x16x32_bf16.
// Block = (y row, co-tile, b); tile 128co x 128x; 4 waves, each 64x64 (4x4 MFMA tiles).
// A and B fragments loaded DIRECTLY from global (k-contiguous 16B per lane):
//   A: lane holds Aw[co=ml][k=q*8+j];  B: lane holds Xp[...][x=ml][ci=q*8+j].
// C/D: col(n/x)=lane&15, row(m/co)=q*4+reg  [verified layout, learn_hip m89].
__global__ __launch_bounds__(256, 2) void k_conv3_mfma(
    const __hip_bfloat16* __restrict__ Xp,   // [b][130][132][256] padded CL
    const __hip_bfloat16* __restrict__ Aw,   // [CO][2304]
    const float* __restrict__ gg, const float* __restrict__ bbp,
    const float* __restrict__ mmp, const float* __restrict__ vvp,
    void* __restrict__ outp, int CO, int bf16out)
{
    const int y    = blockIdx.x;
    const int co0  = blockIdx.y * 128;
    const int b    = blockIdx.z;
    const int t    = threadIdx.x;
    const int lane = t & 63;
    const int w    = t >> 6;
    const int ml   = lane & 15;
    const int q    = lane >> 4;
    const int mbase = (w >> 1) * 64;   // co offset within 128 tile
    const int nbase = (w & 1) * 64;    // x offset

    __shared__ float s_sc[128], s_sh[128];
    if (t < 128) {
        int co = co0 + t;
        float iv = rsqrtf(vvp[co] + EPS);
        float sc = gg[co] * iv;
        s_sc[t] = sc;
        s_sh[t] = bbp[co] - mmp[co] * sc;
    }
    __syncthreads();

    f32x4 acc[4][4];
#pragma unroll
    for (int mt = 0; mt < 4; ++mt)
#pragma unroll
        for (int nt = 0; nt < 4; ++nt)
            acc[mt][nt] = (f32x4){0.f, 0.f, 0.f, 0.f};

    const __hip_bfloat16* ap[4];
#pragma unroll
    for (int mt = 0; mt < 4; ++mt)
        ap[mt] = Aw + (size_t)(co0 + mbase + mt * 16 + ml) * 2304 + q * 8;

    const int kys[9] = {0,0,0,1,1,1,2,2,2};
    const int kxs[9] = {0,1,2,0,1,2,0,1,2};

#pragma unroll 1
    for (int tap = 0; tap < 9; ++tap) {
        const int ky = kys[tap], kx = kxs[tap];
        const __hip_bfloat16* bp[4];
#pragma unroll
        for (int nt = 0; nt < 4; ++nt)
            bp[nt] = Xp + ((size_t)((b * 130 + y + ky) * 132)
                           + nbase + nt * 16 + ml + kx) * 256 + q * 8;
#pragma unroll
        for (int cs = 0; cs < 8; ++cs) {
            bf16x8 af[4], bfv[4];
#pragma unroll
            for (int mt = 0; mt < 4; ++mt)
                af[mt] = *(const bf16x8*)(ap[mt] + cs * 32);
#pragma unroll
            for (int nt = 0; nt < 4; ++nt)
                bfv[nt] = *(const bf16x8*)(bp[nt] + cs * 32);
#pragma unroll
            for (int mt = 0; mt < 4; ++mt)
#pragma unroll
                for (int nt = 0; nt < 4; ++nt)
                    acc[mt][nt] = __builtin_amdgcn_mfma_f32_16x16x32_bf16(
                        af[mt], bfv[nt], acc[mt][nt], 0, 0, 0);
        }
#pragma unroll
        for (int mt = 0; mt < 4; ++mt) ap[mt] += 256;
    }

    // epilogue: BN + relu, write NCHW
#pragma unroll
    for (int mt = 0; mt < 4; ++mt) {
#pragma unroll
        for (int r = 0; r < 4; ++r) {
            int col_co = mbase + mt * 16 + q * 4 + r;
            float sc = s_sc[col_co], sh = s_sh[col_co];
            int co = co0 + col_co;
#pragma unroll
            for (int nt = 0; nt < 4; ++nt) {
                float v = fmaxf(acc[mt][nt][r] * sc + sh, 0.f);
                int x = nbase + nt * 16 + ml;
                size_t oidx = (((size_t)b * CO + co) * HS + y) * WS + x;
                if (bf16out) ((__hip_bfloat16*)outp)[oidx] = __float2bfloat16(v);
                else         ((float*)outp)[oidx] = v;
            }
        }
    }
}

// ---------------------------------------------------------------------------
// Reduce: colmax[b,co,x] = max_y O1;  rowmax[b,co,y] = max_x O2.  (values >= 0)
__global__ __launch_bounds__(128) void k_reduce(
    const __hip_bfloat16* __restrict__ O1, const __hip_bfloat16* __restrict__ O2,
    float* __restrict__ colmax, float* __restrict__ rowmax)
{
    const int bc = blockIdx.x;    // b*128+co
    const int t  = threadIdx.x;
    const __hip_bfloat16* p1 = O1 + (size_t)bc * (HS * WS);
    float m = 0.f;
    for (int yy = 0; yy < HS; ++yy)
        m = fmaxf(m, __bfloat162float(p1[yy * WS + t]));
    colmax[bc * WS + t] = m;

    __shared__ __hip_bfloat16 tile[128 * 132];
    const __hip_bfloat16* p2 = O2 + (size_t)bc * (HS * WS);
    for (int i = t; i < HS * WS; i += 128)
        tile[(i >> 7) * 132 + (i & 127)] = p2[i];
    __syncthreads();
    float m2 = 0.f;
    for (int xx = 0; xx < WS; ++xx)
        m2 = fmaxf(m2, __bfloat162float(tile[t * 132 + xx]));
    rowmax[bc * HS + t] = m2;
}

// ---------------------------------------------------------------------------
// K3: 1-D decomposition of the merge conv (unchanged from round 1).
__global__ __launch_bounds__(128) void k_uv(
    const float* __restrict__ pw, const float* __restrict__ cm,
    const float* __restrict__ rm, float* __restrict__ U, float* __restrict__ V)
{
    const int co   = blockIdx.x;
    const int b    = blockIdx.y;
    const int mode = blockIdx.z;
    const int p    = threadIdx.x;
    float acc0 = 0.f, acc1 = 0.f, acc2 = 0.f;
    const float* base = (mode == 0) ? cm : rm;
    for (int ci = 0; ci < CMID; ++ci) {
        const float* w9 = pw + (co * CMID + ci) * 9;
        float s0[3], s1[3], s2[3];
        if (mode == 0) {
#pragma unroll
            for (int k = 0; k < 3; ++k) {
                float a = w9[k], qq = w9[3 + k], r = w9[6 + k];
                s0[k] = qq + r; s1[k] = a + qq + r; s2[k] = a + qq;
            }
        } else {
#pragma unroll
            for (int k = 0; k < 3; ++k) {
                float a = w9[k*3 + 0], qq = w9[k*3 + 1], r = w9[k*3 + 2];
                s0[k] = qq + r; s1[k] = a + qq + r; s2[k] = a + qq;
            }
        }
        const float* v = base + (b * CMID + ci) * 128;
#pragma unroll
        for (int k = 0; k < 3; ++k) {
            int pos = p + k - 1;
            if ((unsigned)pos < 128u) {
                float vv = v[pos];
                acc0 += s0[k] * vv; acc1 += s1[k] * vv; acc2 += s2[k] * vv;
            }
        }
    }
    float* dst = (mode == 0) ? U : V;
    dst[((0 * NB + b) * CDIM + co) * 128 + p] = acc0;
    dst[((1 * NB + b) * CDIM + co) * 128 + p] = acc1;
    dst[((2 * NB + b) * CDIM + co) * 128 + p] = acc2;
}

// ---------------------------------------------------------------------------
// K4: Rp = relu( psc*(U+V) + psh + csc*conv1x1(x) + csh ), written bf16 padded CL.
__global__ __launch_bounds__(256) void k_merge(
    const float* __restrict__ xin, const float* __restrict__ c1w,
    const float* __restrict__ U, const float* __restrict__ V,
    const float* __restrict__ pg, const float* __restrict__ pb,
    const float* __restrict__ pm, const float* __restrict__ pv,
    const float* __restrict__ cg, const float* __restrict__ cb,
    const float* __restrict__ cmn, const float* __restrict__ cv,
    __hip_bfloat16* __restrict__ Rp)
{
    const int pt  = blockIdx.x;
    const int co0 = blockIdx.y * 64;
    const int b   = blockIdx.z;
    const int p0  = pt * 64;        // 64 consecutive pixels -> single y row
    const int y   = p0 >> 7;
    const int yc  = (y == 0) ? 0 : ((y == HS - 1) ? 2 : 1);
    __shared__ float Xs[8][64];
    __shared__ float Wsh[8][64];
    const int t   = threadIdx.x;
    const int px0 = (t & 15) * 4;
    const int cl0 = (t >> 4) * 4;
    float acc[4][4];   // [co][px]
#pragma unroll
    for (int i = 0; i < 4; ++i)
#pragma unroll
        for (int j = 0; j < 4; ++j) acc[i][j] = 0.f;

    for (int c0 = 0; c0 < CDIM; c0 += 8) {
#pragma unroll
        for (int it = 0; it < 2; ++it) {
            int idx = t + it * 256;
            int cil = idx >> 6, pp = idx & 63;
            Xs[cil][pp] = xin[((size_t)(b * CDIM + c0 + cil)) * (HS * WS) + p0 + pp];
        }
#pragma unroll
        for (int it = 0; it < 2; ++it) {
            int idx = t + it * 256;
            int cwl = idx >> 3, cil = idx & 7;
            Wsh[cil][cwl] = c1w[(co0 + cwl) * CDIM + c0 + cil];
        }
        __syncthreads();
#pragma unroll
        for (int ci = 0; ci < 8; ++ci) {
            float xr[4], wr[4];
#pragma unroll
            for (int j = 0; j < 4; ++j) xr[j] = Xs[ci][px0 + j];
#pragma unroll
            for (int i = 0; i < 4; ++i) wr[i] = Wsh[ci][cl0 + i];
#pragma unroll
            for (int i = 0; i < 4; ++i)
#pragma unroll
                for (int j = 0; j < 4; ++j) acc[i][j] += wr[i] * xr[j];
        }
        __syncthreads();
    }

#pragma unroll
    for (int i = 0; i < 4; ++i) {
        int co = co0 + cl0 + i;
        float iv  = rsqrtf(pv[co] + EPS);
        float psc = pg[co] * iv;
        float psh = pb[co] - pm[co] * psc;
        float iv2 = rsqrtf(cv[co] + EPS);
        float csc = cg[co] * iv2;
        float csh = cb[co] - cmn[co] * csc;
        const float* Urow = U + ((yc * NB + b) * CDIM + co) * 128;
        const float* Vco  = V + ((0 * NB + b) * CDIM + co) * 128;
        float vmid = Vco[(1 * NB) * CDIM * 128 + y];
#pragma unroll
        for (int j = 0; j < 4; ++j) {
            int px = p0 + px0 + j;
            int xx = px & (WS - 1);
            float vterm;
            if (xx == 0)            vterm = Vco[y];
            else if (xx == WS - 1)  vterm = Vco[(2 * NB) * CDIM * 128 + y];
            else                    vterm = vmid;
            float pconv = Urow[xx] + vterm;
            float val = fmaxf(pconv * psc + psh + acc[i][j] * csc + csh, 0.f);
            Rp[((size_t)(b * 130 + y + 1) * 132 + xx + 1) * 256 + co] =
                __float2bfloat16(val);
        }
    }
}

// ---------------------------------------------------------------------------
extern "C" void kernel_launch(void* const* d_in, const int* in_sizes, int n_in,
                              void* d_out, int out_size, void* d_ws, size_t ws_size,
                              hipStream_t stream)
{
    (void)in_sizes; (void)n_in; (void)out_size; (void)ws_size;
    const float* x    = (const float*)d_in[0];
    const float* p1_w = (const float*)d_in[1];
    const float* p1_g = (const float*)d_in[2];
    const float* p1_b = (const float*)d_in[3];
    const float* p1_m = (const float*)d_in[4];
    const float* p1_v = (const float*)d_in[5];
    const float* p2_w = (const float*)d_in[6];
    const float* p2_g = (const float*)d_in[7];
    const float* p2_b = (const float*)d_in[8];
    const float* p2_m = (const float*)d_in[9];
    const float* p2_v = (const float*)d_in[10];
    const float* p_w  = (const float*)d_in[11];
    const float* p_g  = (const float*)d_in[12];
    const float* p_b  = (const float*)d_in[13];
    const float* p_m  = (const float*)d_in[14];
    const float* p_v  = (const float*)d_in[15];
    const float* c1_w = (const float*)d_in[16];
    const float* c1_g = (const float*)d_in[17];
    const float* c1_b = (const float*)d_in[18];
    const float* c1_m = (const float*)d_in[19];
    const float* c1_v = (const float*)d_in[20];
    const float* c2_w = (const float*)d_in[21];
    const float* c2_g = (const float*)d_in[22];
    const float* c2_b = (const float*)d_in[23];
    const float* c2_m = (const float*)d_in[24];
    const float* c2_v = (const float*)d_in[25];
    float* out = (float*)d_out;
    char* ws = (char*)d_ws;

    // workspace layout (bytes) — liveness-aliased, total 70,287,360 B:
    //   [0 .. 35,143,680)              Xp  (bf16 4x130x132x256)
    //       after K2 (Xp dead), sub-allocated:
    //         Aw5    @ 0          (1,179,648)
    //         colmax @ 1,179,648  (262,144)
    //         rowmax @ 1,441,792  (262,144)
    //         U      @ 1,703,936  (1,572,864)
    //         V      @ 3,276,800  (1,572,864)
    //   [35,143,680 .. 70,287,360)     regionA:
    //         O1  @ +0          (16,777,216)   \ dead after k_reduce
    //         O2  @ +16,777,216 (16,777,216)   /
    //         Aw1 @ +33,554,432 (589,824)      \ dead after K1/K2
    //         Aw2 @ +34,144,256 (589,824)      /
    //         Rp  @ +0          (35,143,680)   overwrites all of the above
    constexpr size_t XP_BYTES = (size_t)4 * 130 * 132 * 256 * 2;   // 35,143,680
    char* xp_c  = ws;
    char* ra_c  = ws + XP_BYTES;
    __hip_bfloat16* Xp     = (__hip_bfloat16*)xp_c;
    __hip_bfloat16* Aw5    = (__hip_bfloat16*)(xp_c);
    float*          colmax = (float*)(xp_c + 1179648);
    float*          rowmax = (float*)(xp_c + 1441792);
    float*          Ubuf   = (float*)(xp_c + 1703936);
    float*          Vbuf   = (float*)(xp_c + 3276800);
    __hip_bfloat16* O1     = (__hip_bfloat16*)(ra_c);
    __hip_bfloat16* O2     = (__hip_bfloat16*)(ra_c + 16777216);
    __hip_bfloat16* Aw1    = (__hip_bfloat16*)(ra_c + 33554432);
    __hip_bfloat16* Aw2    = (__hip_bfloat16*)(ra_c + 34144256);
    __hip_bfloat16* Rp     = (__hip_bfloat16*)(ra_c);

    hipMemsetAsync(Xp, 0, XP_BYTES, stream);
    k_xprep<<<dim3(128, 4), 256, 0, stream>>>(x, Xp);
    k_wprep<<<dim3(128), 256, 0, stream>>>(p1_w, Aw1);
    k_wprep<<<dim3(128), 256, 0, stream>>>(p2_w, Aw2);

    k_conv3_mfma<<<dim3(128, 1, 4), 256, 0, stream>>>(
        Xp, Aw1, p1_g, p1_b, p1_m, p1_v, O1, CMID, 1);
    k_conv3_mfma<<<dim3(128, 1, 4), 256, 0, stream>>>(
        Xp, Aw2, p2_g, p2_b, p2_m, p2_v, O2, CMID, 1);

    k_wprep<<<dim3(256), 256, 0, stream>>>(c2_w, Aw5);   // into dead Xp region
    k_reduce<<<dim3(512), 128, 0, stream>>>(O1, O2, colmax, rowmax);

    hipMemsetAsync(Rp, 0, XP_BYTES, stream);             // O1/O2/Aw1/Aw2 dead
    k_uv<<<dim3(256, 4, 2), 128, 0, stream>>>(p_w, colmax, rowmax, Ubuf, Vbuf);
    k_merge<<<dim3(256, 4, 4), 256, 0, stream>>>(
        x, c1_w, Ubuf, Vbuf, p_g, p_b, p_m, p_v,
        c1_g, c1_b, c1_m, c1_v, Rp);

    k_conv3_mfma<<<dim3(128, 2, 4), 256, 0, stream>>>(
        Rp, Aw5, c2_g, c2_b, c2_m, c2_v, out, CDIM, 0);
}

// Round 3
// 660.871 us; speedup vs baseline: 9.5125x; 1.5903x over previous
//
#include <hip/hip_runtime.h>
#include <hip/hip_bf16.h>
#include <math.h>

// pool_cross on MI355X — round 3: LDS-staged MFMA convs (m97 pattern).
//
// All 3x3 convs and the 1x1 merge conv are implicit GEMMs on
// mfma_f32_16x16x32_bf16 with global_load_lds(16B) staging into XOR-swizzled
// LDS and ds_read_b128 fragment reads. Channel-last UNPADDED layouts
// (Xc/Rc [b][y][x][256]); out-of-bounds halo rows redirect the staging
// source to a 256-B zero scratch (global_load_lds src is per-lane, dst is
// wave-uniform+lane*16 — so padding lives in the source select, not LDS).
//
// pool algebra (verified rounds 1-2): bottom(top(a)) = colmax bcast,
// right(left(a)) = rowmax bcast; merge conv input is rank-1 -> 1-D k_uv.

constexpr int NB   = 4;
constexpr int CDIM = 256;
constexpr int CMID = 128;
constexpr int HS   = 128;
constexpr int WS   = 128;
constexpr float EPS = 1e-5f;

typedef __bf16 bf16x8 __attribute__((ext_vector_type(8)));
typedef float  f32x4  __attribute__((ext_vector_type(4)));

#define AS1 __attribute__((address_space(1)))
#define AS3 __attribute__((address_space(3)))

__device__ __forceinline__ void load16_lds(const void* gsrc, void* ldst) {
    __builtin_amdgcn_global_load_lds((const AS1 unsigned int*)gsrc,
                                     (AS3 unsigned int*)ldst, 16, 0, 0);
}

// ---------------------------------------------------------------------------
// P0: x[b][ci][y][x] fp32 -> Xc[b][y][x][ci] bf16 (unpadded channel-last)
__global__ __launch_bounds__(256) void k_xprep(const float* __restrict__ xin,
                                               __hip_bfloat16* __restrict__ Xc)
{
    const int y = blockIdx.x;
    const int b = blockIdx.y;
    const int t = threadIdx.x;
    __shared__ __hip_bfloat16 lds[128 * 66];
    for (int c0 = 0; c0 < CDIM; c0 += 64) {
#pragma unroll
        for (int k = 0; k < 32; ++k) {
            int idx = t + k * 256;
            int ci = idx >> 7;
            int xx = idx & 127;
            float v = xin[(((size_t)b * CDIM + c0 + ci) * HS + y) * WS + xx];
            lds[xx * 66 + ci] = __float2bfloat16(v);
        }
        __syncthreads();
#pragma unroll
        for (int k = 0; k < 32; ++k) {
            int idx = t + k * 256;
            int ci = idx & 63;
            int xx = idx >> 6;
            Xc[((size_t)(b * 128 + y) * 128 + xx) * 256 + c0 + ci] = lds[xx * 66 + ci];
        }
        __syncthreads();
    }
}

// ---------------------------------------------------------------------------
// PW: W[co][ci][3][3] fp32 -> Aw[co][tap*256+ci] bf16 (tap-major K)
__global__ __launch_bounds__(256) void k_wprep(const float* __restrict__ W,
                                               __hip_bfloat16* __restrict__ Aw)
{
    const int co = blockIdx.x;
    const int t  = threadIdx.x;
#pragma unroll
    for (int tap = 0; tap < 9; ++tap)
        Aw[(size_t)co * 2304 + tap * 256 + t] =
            __float2bfloat16(W[((size_t)co * CDIM + t) * 9 + tap]);
}

// PW1: 1x1 weights [256][256] fp32 -> bf16
__global__ __launch_bounds__(256) void k_wprep1(const float* __restrict__ W,
                                                __hip_bfloat16* __restrict__ A)
{
    int i = blockIdx.x * 256 + threadIdx.x;
    A[i] = __float2bfloat16(W[i]);
}

// ---------------------------------------------------------------------------
// Conv3x3 implicit GEMM. Block tile 128co x BNx, one y row. K = 9 taps x 256ci,
// staged in 64-wide chunks: As[128][64] + Bs[BN][64] bf16 in LDS, XOR-swizzled
// by (row&7) so ds_read_b128 spreads over all banks. Wave = 64co x 64x.
template<int BN>
__global__ __launch_bounds__((BN / 64) * 128, 3) void k_conv3(
    const __hip_bfloat16* __restrict__ Xc,   // [b][128][128][256] (or Rc)
    const __hip_bfloat16* __restrict__ Aw,   // [CO][2304]
    const float* __restrict__ zbuf,          // >=128B of zeros
    const float* __restrict__ gg, const float* __restrict__ bbp,
    const float* __restrict__ mmp, const float* __restrict__ vvp,
    void* __restrict__ outp, int CO, int bf16out)
{
    constexpr int THREADS = (BN / 64) * 128;
    constexpr int NXT     = 128 / BN;
    constexpr int NCH     = (128 + BN) * 8;       // 16B chunks per K-step
    constexpr int PASSES  = NCH / THREADS;

    const int y   = blockIdx.x;
    const int cot = blockIdx.y / NXT;
    const int xt  = blockIdx.y % NXT;
    const int b   = blockIdx.z;
    const int co0 = cot * 128;
    const int x0  = xt * BN;

    __shared__ __hip_bfloat16 smem[(128 + BN) * 64];
    __shared__ float s_sc[128], s_sh[128];
    char* smb = (char*)smem;

    const int t    = threadIdx.x;
    const int lane = t & 63;
    const int w    = t >> 6;
    const int ml   = lane & 15;
    const int q    = lane >> 4;
    const int mbase = (BN == 128) ? (w >> 1) * 64 : w * 64;
    const int nbase = (BN == 128) ? (w & 1) * 64 : 0;

    if (t < 128) {
        int co = co0 + t;
        float iv = rsqrtf(vvp[co] + EPS);
        float sc = gg[co] * iv;
        s_sc[t] = sc;
        s_sh[t] = bbp[co] - mmp[co] * sc;
    }

    f32x4 acc[4][4];
#pragma unroll
    for (int mt = 0; mt < 4; ++mt)
#pragma unroll
        for (int nt = 0; nt < 4; ++nt)
            acc[mt][nt] = (f32x4){0.f, 0.f, 0.f, 0.f};

#pragma unroll 1
    for (int ky = 0; ky < 3; ++ky) {
        const int ydata = y + ky - 1;
        if ((unsigned)ydata >= 128u) continue;     // whole tap row contributes 0
#pragma unroll 1
        for (int kx = 0; kx < 3; ++kx) {
            const int tap = ky * 3 + kx;
            const __hip_bfloat16* abase = Aw + (size_t)co0 * 2304 + tap * 256;
            const __hip_bfloat16* bbase = Xc + (size_t)(b * 128 + ydata) * 128 * 256;
#pragma unroll 1
            for (int cih = 0; cih < 4; ++cih) {
                const __hip_bfloat16* ab = abase + cih * 64;
                const __hip_bfloat16* bb = bbase + cih * 64;
#pragma unroll
                for (int p = 0; p < PASSES; ++p) {
                    int i   = t + p * THREADS;
                    int row = i >> 3;
                    int c   = (i & 7) ^ (row & 7);   // source-side swizzle
                    const __hip_bfloat16* src;
                    if (row < 128) {
                        src = ab + (size_t)row * 2304 + c * 8;
                    } else {
                        int gx = x0 + (row - 128) + kx - 1;
                        src = ((unsigned)gx < 128u)
                            ? bb + (size_t)gx * 256 + c * 8
                            : (const __hip_bfloat16*)((const char*)zbuf + c * 16);
                    }
                    load16_lds(src, smb + (size_t)i * 16);
                }
                __syncthreads();
#pragma unroll
                for (int s = 0; s < 2; ++s) {
                    const int coff = ((s * 4 + q) ^ (ml & 7)) * 16;
                    bf16x8 af[4], bfv[4];
#pragma unroll
                    for (int mt = 0; mt < 4; ++mt)
                        af[mt] = *(const bf16x8*)(smb + (size_t)(mbase + mt * 16 + ml) * 128 + coff);
#pragma unroll
                    for (int nt = 0; nt < 4; ++nt)
                        bfv[nt] = *(const bf16x8*)(smb + (size_t)(128 + nbase + nt * 16 + ml) * 128 + coff);
#pragma unroll
                    for (int mt = 0; mt < 4; ++mt)
#pragma unroll
                        for (int nt = 0; nt < 4; ++nt)
                            acc[mt][nt] = __builtin_amdgcn_mfma_f32_16x16x32_bf16(
                                af[mt], bfv[nt], acc[mt][nt], 0, 0, 0);
                }
                __syncthreads();
            }
        }
    }

    // epilogue: BN+relu, NCHW out. C/D: col(x)=ml, row(co)=q*4+r.
#pragma unroll
    for (int mt = 0; mt < 4; ++mt) {
#pragma unroll
        for (int r = 0; r < 4; ++r) {
            const int col = mbase + mt * 16 + q * 4 + r;
            const float sc = s_sc[col], sh = s_sh[col];
            const int co = co0 + col;
#pragma unroll
            for (int nt = 0; nt < 4; ++nt) {
                float v = fmaxf(acc[mt][nt][r] * sc + sh, 0.f);
                const int x = x0 + nbase + nt * 16 + ml;
                const size_t oidx = (((size_t)b * CO + co) * HS + y) * WS + x;
                if (bf16out) ((__hip_bfloat16*)outp)[oidx] = __float2bfloat16(v);
                else         ((float*)outp)[oidx] = v;
            }
        }
    }
}

// ---------------------------------------------------------------------------
// Reduce: colmax[b,co,x] = max_y O1;  rowmax[b,co,y] = max_x O2.
__global__ __launch_bounds__(128) void k_reduce(
    const __hip_bfloat16* __restrict__ O1, const __hip_bfloat16* __restrict__ O2,
    float* __restrict__ colmax, float* __restrict__ rowmax)
{
    const int bc = blockIdx.x;
    const int t  = threadIdx.x;
    const __hip_bfloat16* p1 = O1 + (size_t)bc * (HS * WS);
    float m = 0.f;
    for (int yy = 0; yy < HS; ++yy)
        m = fmaxf(m, __bfloat162float(p1[yy * WS + t]));
    colmax[bc * WS + t] = m;

    __shared__ __hip_bfloat16 tile[128 * 132];
    const __hip_bfloat16* p2 = O2 + (size_t)bc * (HS * WS);
    for (int i = t; i < HS * WS; i += 128)
        tile[(i >> 7) * 132 + (i & 127)] = p2[i];
    __syncthreads();
    float m2 = 0.f;
    for (int xx = 0; xx < WS; ++xx)
        m2 = fmaxf(m2, __bfloat162float(tile[t * 132 + xx]));
    rowmax[bc * HS + t] = m2;
}

// ---------------------------------------------------------------------------
// K3: 1-D decomposition of the merge conv -> U,V (bf16 out).
__global__ __launch_bounds__(128) void k_uv(
    const float* __restrict__ pw, const float* __restrict__ cm,
    const float* __restrict__ rm,
    __hip_bfloat16* __restrict__ U, __hip_bfloat16* __restrict__ V)
{
    const int co   = blockIdx.x;
    const int b    = blockIdx.y;
    const int mode = blockIdx.z;
    const int p    = threadIdx.x;
    float acc0 = 0.f, acc1 = 0.f, acc2 = 0.f;
    const float* base = (mode == 0) ? cm : rm;
    for (int ci = 0; ci < CMID; ++ci) {
        const float* w9 = pw + (co * CMID + ci) * 9;
        float s0[3], s1[3], s2[3];
        if (mode == 0) {
#pragma unroll
            for (int k = 0; k < 3; ++k) {
                float a = w9[k], qq = w9[3 + k], r = w9[6 + k];
                s0[k] = qq + r; s1[k] = a + qq + r; s2[k] = a + qq;
            }
        } else {
#pragma unroll
            for (int k = 0; k < 3; ++k) {
                float a = w9[k*3 + 0], qq = w9[k*3 + 1], r = w9[k*3 + 2];
                s0[k] = qq + r; s1[k] = a + qq + r; s2[k] = a + qq;
            }
        }
        const float* v = base + (b * CMID + ci) * 128;
#pragma unroll
        for (int k = 0; k < 3; ++k) {
            int pos = p + k - 1;
            if ((unsigned)pos < 128u) {
                float vv = v[pos];
                acc0 += s0[k] * vv; acc1 += s1[k] * vv; acc2 += s2[k] * vv;
            }
        }
    }
    __hip_bfloat16* dst = (mode == 0) ? U : V;
    dst[((0 * NB + b) * CDIM + co) * 128 + p] = __float2bfloat16(acc0);
    dst[((1 * NB + b) * CDIM + co) * 128 + p] = __float2bfloat16(acc1);
    dst[((2 * NB + b) * CDIM + co) * 128 + p] = __float2bfloat16(acc2);
}

// ---------------------------------------------------------------------------
// K4: merge as MFMA GEMM. Rc[b][y][x][co] = relu(psc*(U+V)+psh + csc*xw+csh),
// xw = 1x1 conv of Xc row y. Tile 128co x 128x, K=256 in 4 steps.
__global__ __launch_bounds__(256, 3) void k_merge_mfma(
    const __hip_bfloat16* __restrict__ Xc, const __hip_bfloat16* __restrict__ Aw4,
    const __hip_bfloat16* __restrict__ U, const __hip_bfloat16* __restrict__ V,
    const float* __restrict__ pg, const float* __restrict__ pb,
    const float* __restrict__ pm, const float* __restrict__ pv,
    const float* __restrict__ cg, const float* __restrict__ cb,
    const float* __restrict__ cmn, const float* __restrict__ cv,
    __hip_bfloat16* __restrict__ Rc)
{
    const int y   = blockIdx.x;
    const int cot = blockIdx.y;
    const int b   = blockIdx.z;
    const int co0 = cot * 128;
    __shared__ __hip_bfloat16 smem[256 * 64];
    __shared__ float s_psc[128], s_psh[128], s_csc[128], s_csh[128];
    __shared__ float s_v0[128], s_vm[128], s_v1[128];
    char* smb = (char*)smem;
    const int t = threadIdx.x, lane = t & 63, w = t >> 6;
    const int ml = lane & 15, q = lane >> 4;
    const int mbase = (w >> 1) * 64, nbase = (w & 1) * 64;
    const int yc = (y == 0) ? 0 : ((y == HS - 1) ? 2 : 1);

    if (t < 128) {
        int co = co0 + t;
        float iv = rsqrtf(pv[co] + EPS);
        float psc = pg[co] * iv;
        s_psc[t] = psc;
        s_psh[t] = pb[co] - pm[co] * psc;
        float iv2 = rsqrtf(cv[co] + EPS);
        float csc = cg[co] * iv2;
        s_csc[t] = csc;
        s_csh[t] = cb[co] - cmn[co] * csc;
        const size_t vb = ((size_t)b * CDIM + co) * 128 + y;
        const size_t cstr = (size_t)NB * CDIM * 128;
        s_v0[t] = __bfloat162float(V[vb]);
        s_vm[t] = __bfloat162float(V[cstr + vb]);
        s_v1[t] = __bfloat162float(V[2 * cstr + vb]);
    }

    f32x4 acc[4][4];
#pragma unroll
    for (int mt = 0; mt < 4; ++mt)
#pragma unroll
        for (int nt = 0; nt < 4; ++nt)
            acc[mt][nt] = (f32x4){0.f, 0.f, 0.f, 0.f};

    const __hip_bfloat16* brow = Xc + (size_t)(b * 128 + y) * 128 * 256;
#pragma unroll 1
    for (int ks = 0; ks < 4; ++ks) {
        const __hip_bfloat16* ab = Aw4 + (size_t)co0 * 256 + ks * 64;
        const __hip_bfloat16* bb = brow + ks * 64;
#pragma unroll
        for (int p = 0; p < 8; ++p) {
            int i   = t + p * 256;
            int row = i >> 3;
            int c   = (i & 7) ^ (row & 7);
            const __hip_bfloat16* src = (row < 128)
                ? ab + (size_t)row * 256 + c * 8
                : bb + (size_t)(row - 128) * 256 + c * 8;
            load16_lds(src, smb + (size_t)i * 16);
        }
        __syncthreads();
#pragma unroll
        for (int s = 0; s < 2; ++s) {
            const int coff = ((s * 4 + q) ^ (ml & 7)) * 16;
            bf16x8 af[4], bfv[4];
#pragma unroll
            for (int mt = 0; mt < 4; ++mt)
                af[mt] = *(const bf16x8*)(smb + (size_t)(mbase + mt * 16 + ml) * 128 + coff);
#pragma unroll
            for (int nt = 0; nt < 4; ++nt)
                bfv[nt] = *(const bf16x8*)(smb + (size_t)(128 + nbase + nt * 16 + ml) * 128 + coff);
#pragma unroll
            for (int mt = 0; mt < 4; ++mt)
#pragma unroll
                for (int nt = 0; nt < 4; ++nt)
                    acc[mt][nt] = __builtin_amdgcn_mfma_f32_16x16x32_bf16(
                        af[mt], bfv[nt], acc[mt][nt], 0, 0, 0);
        }
        __syncthreads();
    }

    const __hip_bfloat16* Ub = U + ((size_t)(yc * NB + b) * CDIM + co0) * 128;
#pragma unroll
    for (int mt = 0; mt < 4; ++mt) {
#pragma unroll
        for (int nt = 0; nt < 4; ++nt) {
            const int x = nbase + nt * 16 + ml;
            unsigned long long pk = 0;
#pragma unroll
            for (int r = 0; r < 4; ++r) {
                const int col = mbase + mt * 16 + q * 4 + r;
                float u  = __bfloat162float(Ub[(size_t)col * 128 + x]);
                float vt = (x == 0) ? s_v0[col] : ((x == WS - 1) ? s_v1[col] : s_vm[col]);
                float val = fmaxf((u + vt) * s_psc[col] + s_psh[col]
                                  + acc[mt][nt][r] * s_csc[col] + s_csh[col], 0.f);
                __hip_bfloat16 hb = __float2bfloat16(val);
                unsigned short bits;
                __builtin_memcpy(&bits, &hb, 2);
                pk |= (unsigned long long)bits << (16 * r);
            }
            *(unsigned long long*)((char*)Rc +
                ((size_t)((b * 128 + y) * 128 + x) * 256 + co0 + mbase + mt * 16 + q * 4) * 2) = pk;
        }
    }
}

// ---------------------------------------------------------------------------
extern "C" void kernel_launch(void* const* d_in, const int* in_sizes, int n_in,
                              void* d_out, int out_size, void* d_ws, size_t ws_size,
                              hipStream_t stream)
{
    (void)in_sizes; (void)n_in; (void)out_size; (void)ws_size;
    const float* x    = (const float*)d_in[0];
    const float* p1_w = (const float*)d_in[1];
    const float* p1_g = (const float*)d_in[2];
    const float* p1_b = (const float*)d_in[3];
    const float* p1_m = (const float*)d_in[4];
    const float* p1_v = (const float*)d_in[5];
    const float* p2_w = (const float*)d_in[6];
    const float* p2_g = (const float*)d_in[7];
    const float* p2_b = (const float*)d_in[8];
    const float* p2_m = (const float*)d_in[9];
    const float* p2_v = (const float*)d_in[10];
    const float* p_w  = (const float*)d_in[11];
    const float* p_g  = (const float*)d_in[12];
    const float* p_b  = (const float*)d_in[13];
    const float* p_m  = (const float*)d_in[14];
    const float* p_v  = (const float*)d_in[15];
    const float* c1_w = (const float*)d_in[16];
    const float* c1_g = (const float*)d_in[17];
    const float* c1_b = (const float*)d_in[18];
    const float* c1_m = (const float*)d_in[19];
    const float* c1_v = (const float*)d_in[20];
    const float* c2_w = (const float*)d_in[21];
    const float* c2_g = (const float*)d_in[22];
    const float* c2_b = (const float*)d_in[23];
    const float* c2_m = (const float*)d_in[24];
    const float* c2_v = (const float*)d_in[25];
    float* out = (float*)d_out;
    char* ws = (char*)d_ws;

    // layout (bytes), total 69,337,344 (<= proven-safe 70,778,880):
    //   Xc   @ 0           (33,554,432)  live: xprep .. k_merge; then Aw5 aliases
    //   regB @ 33,554,432  (33,554,432)  O1 @+0, O2 @+16,777,216 (dead after
    //                                    k_reduce); Rc @+0 aliases both
    //   Aw4  @ 67,108,864  (131,072)
    //   cmax @ 67,239,936  (262,144)
    //   rmax @ 67,502,080  (262,144)
    //   regE @ 67,764,224  (1,572,864)   Aw1 @+0, Aw2 @+589,824 (dead after
    //                                    K1/K2); U @+0, V @+786,432 alias them
    //   zbuf @ 69,337,088  (256)
    __hip_bfloat16* Xc   = (__hip_bfloat16*)ws;
    char* regB = ws + 33554432;
    __hip_bfloat16* O1   = (__hip_bfloat16*)regB;
    __hip_bfloat16* O2   = (__hip_bfloat16*)(regB + 16777216);
    __hip_bfloat16* Rc   = (__hip_bfloat16*)regB;
    __hip_bfloat16* Aw4  = (__hip_bfloat16*)(ws + 67108864);
    float*          cmax = (float*)(ws + 67239936);
    float*          rmax = (float*)(ws + 67502080);
    char* regE = ws + 67764224;
    __hip_bfloat16* Aw1  = (__hip_bfloat16*)regE;
    __hip_bfloat16* Aw2  = (__hip_bfloat16*)(regE + 589824);
    __hip_bfloat16* Ubuf = (__hip_bfloat16*)regE;
    __hip_bfloat16* Vbuf = (__hip_bfloat16*)(regE + 786432);
    float*          zbuf = (float*)(ws + 69337088);
    __hip_bfloat16* Aw5  = (__hip_bfloat16*)ws;   // aliases Xc, written post-merge

    hipMemsetAsync(zbuf, 0, 256, stream);
    k_xprep<<<dim3(128, 4), 256, 0, stream>>>(x, Xc);
    k_wprep<<<dim3(128), 256, 0, stream>>>(p1_w, Aw1);
    k_wprep<<<dim3(128), 256, 0, stream>>>(p2_w, Aw2);
    k_wprep1<<<dim3(256), 256, 0, stream>>>(c1_w, Aw4);

    k_conv3<64><<<dim3(128, 2, 4), 128, 0, stream>>>(
        Xc, Aw1, zbuf, p1_g, p1_b, p1_m, p1_v, O1, CMID, 1);
    k_conv3<64><<<dim3(128, 2, 4), 128, 0, stream>>>(
        Xc, Aw2, zbuf, p2_g, p2_b, p2_m, p2_v, O2, CMID, 1);

    k_reduce<<<dim3(512), 128, 0, stream>>>(O1, O2, cmax, rmax);
    k_uv<<<dim3(256, 4, 2), 128, 0, stream>>>(p_w, cmax, rmax, Ubuf, Vbuf);

    k_merge_mfma<<<dim3(128, 2, 4), 256, 0, stream>>>(
        Xc, Aw4, Ubuf, Vbuf, p_g, p_b, p_m, p_v,
        c1_g, c1_b, c1_m, c1_v, Rc);

    k_wprep<<<dim3(256), 256, 0, stream>>>(c2_w, Aw5);   // Xc dead now
    k_conv3<128><<<dim3(128, 2, 4), 256, 0, stream>>>(
        Rc, Aw5, zbuf, c2_g, c2_b, c2_m, c2_v, out, CDIM, 0);
}

// Round 4
// 433.886 us; speedup vs baseline: 14.4889x; 1.5231x over previous
//
#include <hip/hip_runtime.h>
#include <hip/hip_bf16.h>
#include <math.h>

// pool_cross on MI355X — round 4: ky-level staging with kx-shift LDS reuse.
//
// Conv3x3 K-loop restructured: per (ky, 64-ci chunk) stage A for all 3 kx
// taps (K-contiguous in tap-major Aw) + ONE haloed B row (130 x-positions),
// serve all 3 kx taps from the same staging via shifted LDS rows.
// 96 MFMA per barrier-pair per wave (was 32), 12 pairs per block (was 36),
// B staging cut 3x. Tile 128co x 128x, 256 threads, LDS 66.8 KB (2 blk/CU).
//
// pool algebra (verified): bottom(top(a)) = colmax bcast, right(left(a)) =
// rowmax bcast; merge conv input is rank-1 -> 1-D k_uv decomposition.

constexpr int NB   = 4;
constexpr int CDIM = 256;
constexpr int CMID = 128;
constexpr int HS   = 128;
constexpr int WS   = 128;
constexpr float EPS = 1e-5f;

typedef __bf16 bf16x8 __attribute__((ext_vector_type(8)));
typedef float  f32x4  __attribute__((ext_vector_type(4)));

#define AS1 __attribute__((address_space(1)))
#define AS3 __attribute__((address_space(3)))

__device__ __forceinline__ void load16_lds(const void* gsrc, void* ldst) {
    __builtin_amdgcn_global_load_lds((const AS1 unsigned int*)gsrc,
                                     (AS3 unsigned int*)ldst, 16, 0, 0);
}

// ---------------------------------------------------------------------------
// P0: x[b][ci][y][x] fp32 -> Xc[b][y][x][ci] bf16 (unpadded channel-last)
__global__ __launch_bounds__(256) void k_xprep(const float* __restrict__ xin,
                                               __hip_bfloat16* __restrict__ Xc)
{
    const int y = blockIdx.x;
    const int b = blockIdx.y;
    const int t = threadIdx.x;
    __shared__ __hip_bfloat16 lds[128 * 66];
    for (int c0 = 0; c0 < CDIM; c0 += 64) {
#pragma unroll
        for (int k = 0; k < 32; ++k) {
            int idx = t + k * 256;
            int ci = idx >> 7;
            int xx = idx & 127;
            float v = xin[(((size_t)b * CDIM + c0 + ci) * HS + y) * WS + xx];
            lds[xx * 66 + ci] = __float2bfloat16(v);
        }
        __syncthreads();
#pragma unroll
        for (int k = 0; k < 32; ++k) {
            int idx = t + k * 256;
            int ci = idx & 63;
            int xx = idx >> 6;
            Xc[((size_t)(b * 128 + y) * 128 + xx) * 256 + c0 + ci] = lds[xx * 66 + ci];
        }
        __syncthreads();
    }
}

// ---------------------------------------------------------------------------
// PW: W[co][ci][3][3] fp32 -> Aw[co][tap*256+ci] bf16 (tap-major K)
__global__ __launch_bounds__(256) void k_wprep(const float* __restrict__ W,
                                               __hip_bfloat16* __restrict__ Aw)
{
    const int co = blockIdx.x;
    const int t  = threadIdx.x;
#pragma unroll
    for (int tap = 0; tap < 9; ++tap)
        Aw[(size_t)co * 2304 + tap * 256 + t] =
            __float2bfloat16(W[((size_t)co * CDIM + t) * 9 + tap]);
}

// PW1: 1x1 weights [256][256] fp32 -> bf16
__global__ __launch_bounds__(256) void k_wprep1(const float* __restrict__ W,
                                                __hip_bfloat16* __restrict__ A)
{
    int i = blockIdx.x * 256 + threadIdx.x;
    A[i] = __float2bfloat16(W[i]);
}

// ---------------------------------------------------------------------------
// Conv3x3 implicit GEMM, tile 128co x 128x (full width), one y row.
// LDS per (ky, cih) step: A rows 0..383 (row = kx*128 + co_l, 128B = 64 ci),
// B rows 384..513 (row = 384 + xi, gx = xi-1, halo -> zbuf). XOR-swizzled
// 16B chunks (chunk slot = (cl ^ (row&7))). 4 waves, each 64co x 64x.
__global__ __launch_bounds__(256, 2) void k_conv3(
    const __hip_bfloat16* __restrict__ Xc,   // [b][128][128][256] (or Rc)
    const __hip_bfloat16* __restrict__ Aw,   // [CO][2304]
    const float* __restrict__ zbuf,          // >=256B of zeros
    const float* __restrict__ gg, const float* __restrict__ bbp,
    const float* __restrict__ mmp, const float* __restrict__ vvp,
    void* __restrict__ outp, int CO, int bf16out)
{
    const int y   = blockIdx.x;
    const int co0 = blockIdx.y * 128;
    const int b   = blockIdx.z;

    __shared__ __hip_bfloat16 smem[514 * 64];   // 514 rows x 128 B = 65,792 B
    __shared__ float s_sc[128], s_sh[128];
    char* smb = (char*)smem;

    const int t    = threadIdx.x;
    const int lane = t & 63;
    const int w    = t >> 6;
    const int ml   = lane & 15;
    const int q    = lane >> 4;
    const int mbase = (w >> 1) * 64;
    const int nbase = (w & 1) * 64;

    if (t < 128) {
        int co = co0 + t;
        float iv = rsqrtf(vvp[co] + EPS);
        float sc = gg[co] * iv;
        s_sc[t] = sc;
        s_sh[t] = bbp[co] - mmp[co] * sc;
    }

    f32x4 acc[4][4];
#pragma unroll
    for (int mt = 0; mt < 4; ++mt)
#pragma unroll
        for (int nt = 0; nt < 4; ++nt)
            acc[mt][nt] = (f32x4){0.f, 0.f, 0.f, 0.f};

#pragma unroll 1
    for (int ky = 0; ky < 3; ++ky) {
        const int ydata = y + ky - 1;
        if ((unsigned)ydata >= 128u) continue;     // zero-padded tap row
        const __hip_bfloat16* arow = Aw + (size_t)co0 * 2304 + (3 * ky) * 256;
        const __hip_bfloat16* brow = Xc + (size_t)(b * 128 + ydata) * 128 * 256;
#pragma unroll 1
        for (int cih = 0; cih < 4; ++cih) {
            // ---- stage 514 rows x 8 chunks = 4112 x 16B ----
#pragma unroll
            for (int p = 0; p < 17; ++p) {
                int i = t + p * 256;
                if (i < 4112) {
                    int row = i >> 3;
                    int cl  = (i & 7) ^ (row & 7);   // logical chunk
                    const __hip_bfloat16* src;
                    if (row < 384) {
                        int j    = row >> 7;         // kx
                        int co_l = row & 127;
                        src = arow + (size_t)co_l * 2304 + j * 256 + cih * 64 + cl * 8;
                    } else {
                        int gx = (row - 384) - 1;
                        src = ((unsigned)gx < 128u)
                            ? brow + (size_t)gx * 256 + cih * 64 + cl * 8
                            : (const __hip_bfloat16*)((const char*)zbuf + cl * 16);
                    }
                    load16_lds(src, smb + (size_t)i * 16);
                }
            }
            __syncthreads();
            // ---- 3 kx taps x 2 k-substeps x 16 MFMA per wave ----
#pragma unroll
            for (int j = 0; j < 3; ++j) {
#pragma unroll
                for (int s = 0; s < 2; ++s) {
                    bf16x8 af[4], bfv[4];
#pragma unroll
                    for (int mt = 0; mt < 4; ++mt) {
                        const int ra = j * 128 + mbase + mt * 16 + ml;
                        const int coff = ((s * 4 + q) ^ (ra & 7)) * 16;
                        af[mt] = *(const bf16x8*)(smb + (size_t)ra * 128 + coff);
                    }
#pragma unroll
                    for (int nt = 0; nt < 4; ++nt) {
                        const int rb = 384 + nbase + nt * 16 + ml + j;
                        const int coff = ((s * 4 + q) ^ (rb & 7)) * 16;
                        bfv[nt] = *(const bf16x8*)(smb + (size_t)rb * 128 + coff);
                    }
#pragma unroll
                    for (int mt = 0; mt < 4; ++mt)
#pragma unroll
                        for (int nt = 0; nt < 4; ++nt)
                            acc[mt][nt] = __builtin_amdgcn_mfma_f32_16x16x32_bf16(
                                af[mt], bfv[nt], acc[mt][nt], 0, 0, 0);
                }
            }
            __syncthreads();
        }
    }

    // epilogue: BN+relu, NCHW out. C/D: col(x)=ml, row(co)=q*4+r.
#pragma unroll
    for (int mt = 0; mt < 4; ++mt) {
#pragma unroll
        for (int r = 0; r < 4; ++r) {
            const int col = mbase + mt * 16 + q * 4 + r;
            const float sc = s_sc[col], sh = s_sh[col];
            const int co = co0 + col;
#pragma unroll
            for (int nt = 0; nt < 4; ++nt) {
                float v = fmaxf(acc[mt][nt][r] * sc + sh, 0.f);
                const int x = nbase + nt * 16 + ml;
                const size_t oidx = (((size_t)b * CO + co) * HS + y) * WS + x;
                if (bf16out) ((__hip_bfloat16*)outp)[oidx] = __float2bfloat16(v);
                else         ((float*)outp)[oidx] = v;
            }
        }
    }
}

// ---------------------------------------------------------------------------
// Reduce: colmax[b,co,x] = max_y O1;  rowmax[b,co,y] = max_x O2.
__global__ __launch_bounds__(128) void k_reduce(
    const __hip_bfloat16* __restrict__ O1, const __hip_bfloat16* __restrict__ O2,
    float* __restrict__ colmax, float* __restrict__ rowmax)
{
    const int bc = blockIdx.x;
    const int t  = threadIdx.x;
    const __hip_bfloat16* p1 = O1 + (size_t)bc * (HS * WS);
    float m = 0.f;
    for (int yy = 0; yy < HS; ++yy)
        m = fmaxf(m, __bfloat162float(p1[yy * WS + t]));
    colmax[bc * WS + t] = m;

    __shared__ __hip_bfloat16 tile[128 * 132];
    const __hip_bfloat16* p2 = O2 + (size_t)bc * (HS * WS);
    for (int i = t; i < HS * WS; i += 128)
        tile[(i >> 7) * 132 + (i & 127)] = p2[i];
    __syncthreads();
    float m2 = 0.f;
    for (int xx = 0; xx < WS; ++xx)
        m2 = fmaxf(m2, __bfloat162float(tile[t * 132 + xx]));
    rowmax[bc * HS + t] = m2;
}

// ---------------------------------------------------------------------------
// K3: 1-D decomposition of the merge conv -> U,V (bf16 out).
__global__ __launch_bounds__(128) void k_uv(
    const float* __restrict__ pw, const float* __restrict__ cm,
    const float* __restrict__ rm,
    __hip_bfloat16* __restrict__ U, __hip_bfloat16* __restrict__ V)
{
    const int co   = blockIdx.x;
    const int b    = blockIdx.y;
    const int mode = blockIdx.z;
    const int p    = threadIdx.x;
    float acc0 = 0.f, acc1 = 0.f, acc2 = 0.f;
    const float* base = (mode == 0) ? cm : rm;
    for (int ci = 0; ci < CMID; ++ci) {
        const float* w9 = pw + (co * CMID + ci) * 9;
        float s0[3], s1[3], s2[3];
        if (mode == 0) {
#pragma unroll
            for (int k = 0; k < 3; ++k) {
                float a = w9[k], qq = w9[3 + k], r = w9[6 + k];
                s0[k] = qq + r; s1[k] = a + qq + r; s2[k] = a + qq;
            }
        } else {
#pragma unroll
            for (int k = 0; k < 3; ++k) {
                float a = w9[k*3 + 0], qq = w9[k*3 + 1], r = w9[k*3 + 2];
                s0[k] = qq + r; s1[k] = a + qq + r; s2[k] = a + qq;
            }
        }
        const float* v = base + (b * CMID + ci) * 128;
#pragma unroll
        for (int k = 0; k < 3; ++k) {
            int pos = p + k - 1;
            if ((unsigned)pos < 128u) {
                float vv = v[pos];
                acc0 += s0[k] * vv; acc1 += s1[k] * vv; acc2 += s2[k] * vv;
            }
        }
    }
    __hip_bfloat16* dst = (mode == 0) ? U : V;
    dst[((0 * NB + b) * CDIM + co) * 128 + p] = __float2bfloat16(acc0);
    dst[((1 * NB + b) * CDIM + co) * 128 + p] = __float2bfloat16(acc1);
    dst[((2 * NB + b) * CDIM + co) * 128 + p] = __float2bfloat16(acc2);
}

// ---------------------------------------------------------------------------
// K4: merge as MFMA GEMM. Rc[b][y][x][co] = relu(psc*(U+V)+psh + csc*xw+csh).
__global__ __launch_bounds__(256, 3) void k_merge_mfma(
    const __hip_bfloat16* __restrict__ Xc, const __hip_bfloat16* __restrict__ Aw4,
    const __hip_bfloat16* __restrict__ U, const __hip_bfloat16* __restrict__ V,
    const float* __restrict__ pg, const float* __restrict__ pb,
    const float* __restrict__ pm, const float* __restrict__ pv,
    const float* __restrict__ cg, const float* __restrict__ cb,
    const float* __restrict__ cmn, const float* __restrict__ cv,
    __hip_bfloat16* __restrict__ Rc)
{
    const int y   = blockIdx.x;
    const int cot = blockIdx.y;
    const int b   = blockIdx.z;
    const int co0 = cot * 128;
    __shared__ __hip_bfloat16 smem[256 * 64];
    __shared__ float s_psc[128], s_psh[128], s_csc[128], s_csh[128];
    __shared__ float s_v0[128], s_vm[128], s_v1[128];
    char* smb = (char*)smem;
    const int t = threadIdx.x, lane = t & 63, w = t >> 6;
    const int ml = lane & 15, q = lane >> 4;
    const int mbase = (w >> 1) * 64, nbase = (w & 1) * 64;
    const int yc = (y == 0) ? 0 : ((y == HS - 1) ? 2 : 1);

    if (t < 128) {
        int co = co0 + t;
        float iv = rsqrtf(pv[co] + EPS);
        float psc = pg[co] * iv;
        s_psc[t] = psc;
        s_psh[t] = pb[co] - pm[co] * psc;
        float iv2 = rsqrtf(cv[co] + EPS);
        float csc = cg[co] * iv2;
        s_csc[t] = csc;
        s_csh[t] = cb[co] - cmn[co] * csc;
        const size_t vb = ((size_t)b * CDIM + co) * 128 + y;
        const size_t cstr = (size_t)NB * CDIM * 128;
        s_v0[t] = __bfloat162float(V[vb]);
        s_vm[t] = __bfloat162float(V[cstr + vb]);
        s_v1[t] = __bfloat162float(V[2 * cstr + vb]);
    }

    f32x4 acc[4][4];
#pragma unroll
    for (int mt = 0; mt < 4; ++mt)
#pragma unroll
        for (int nt = 0; nt < 4; ++nt)
            acc[mt][nt] = (f32x4){0.f, 0.f, 0.f, 0.f};

    const __hip_bfloat16* brow = Xc + (size_t)(b * 128 + y) * 128 * 256;
#pragma unroll 1
    for (int ks = 0; ks < 4; ++ks) {
        const __hip_bfloat16* ab = Aw4 + (size_t)co0 * 256 + ks * 64;
        const __hip_bfloat16* bb = brow + ks * 64;
#pragma unroll
        for (int p = 0; p < 8; ++p) {
            int i   = t + p * 256;
            int row = i >> 3;
            int c   = (i & 7) ^ (row & 7);
            const __hip_bfloat16* src = (row < 128)
                ? ab + (size_t)row * 256 + c * 8
                : bb + (size_t)(row - 128) * 256 + c * 8;
            load16_lds(src, smb + (size_t)i * 16);
        }
        __syncthreads();
#pragma unroll
        for (int s = 0; s < 2; ++s) {
            const int coff = ((s * 4 + q) ^ (ml & 7)) * 16;
            bf16x8 af[4], bfv[4];
#pragma unroll
            for (int mt = 0; mt < 4; ++mt)
                af[mt] = *(const bf16x8*)(smb + (size_t)(mbase + mt * 16 + ml) * 128 + coff);
#pragma unroll
            for (int nt = 0; nt < 4; ++nt)
                bfv[nt] = *(const bf16x8*)(smb + (size_t)(128 + nbase + nt * 16 + ml) * 128 + coff);
#pragma unroll
            for (int mt = 0; mt < 4; ++mt)
#pragma unroll
                for (int nt = 0; nt < 4; ++nt)
                    acc[mt][nt] = __builtin_amdgcn_mfma_f32_16x16x32_bf16(
                        af[mt], bfv[nt], acc[mt][nt], 0, 0, 0);
        }
        __syncthreads();
    }

    const __hip_bfloat16* Ub = U + ((size_t)(yc * NB + b) * CDIM + co0) * 128;
#pragma unroll
    for (int mt = 0; mt < 4; ++mt) {
#pragma unroll
        for (int nt = 0; nt < 4; ++nt) {
            const int x = nbase + nt * 16 + ml;
            unsigned long long pk = 0;
#pragma unroll
            for (int r = 0; r < 4; ++r) {
                const int col = mbase + mt * 16 + q * 4 + r;
                float u  = __bfloat162float(Ub[(size_t)col * 128 + x]);
                float vt = (x == 0) ? s_v0[col] : ((x == WS - 1) ? s_v1[col] : s_vm[col]);
                float val = fmaxf((u + vt) * s_psc[col] + s_psh[col]
                                  + acc[mt][nt][r] * s_csc[col] + s_csh[col], 0.f);
                __hip_bfloat16 hb = __float2bfloat16(val);
                unsigned short bits;
                __builtin_memcpy(&bits, &hb, 2);
                pk |= (unsigned long long)bits << (16 * r);
            }
            *(unsigned long long*)((char*)Rc +
                ((size_t)((b * 128 + y) * 128 + x) * 256 + co0 + mbase + mt * 16 + q * 4) * 2) = pk;
        }
    }
}

// ---------------------------------------------------------------------------
extern "C" void kernel_launch(void* const* d_in, const int* in_sizes, int n_in,
                              void* d_out, int out_size, void* d_ws, size_t ws_size,
                              hipStream_t stream)
{
    (void)in_sizes; (void)n_in; (void)out_size; (void)ws_size;
    const float* x    = (const float*)d_in[0];
    const float* p1_w = (const float*)d_in[1];
    const float* p1_g = (const float*)d_in[2];
    const float* p1_b = (const float*)d_in[3];
    const float* p1_m = (const float*)d_in[4];
    const float* p1_v = (const float*)d_in[5];
    const float* p2_w = (const float*)d_in[6];
    const float* p2_g = (const float*)d_in[7];
    const float* p2_b = (const float*)d_in[8];
    const float* p2_m = (const float*)d_in[9];
    const float* p2_v = (const float*)d_in[10];
    const float* p_w  = (const float*)d_in[11];
    const float* p_g  = (const float*)d_in[12];
    const float* p_b  = (const float*)d_in[13];
    const float* p_m  = (const float*)d_in[14];
    const float* p_v  = (const float*)d_in[15];
    const float* c1_w = (const float*)d_in[16];
    const float* c1_g = (const float*)d_in[17];
    const float* c1_b = (const float*)d_in[18];
    const float* c1_m = (const float*)d_in[19];
    const float* c1_v = (const float*)d_in[20];
    const float* c2_w = (const float*)d_in[21];
    const float* c2_g = (const float*)d_in[22];
    const float* c2_b = (const float*)d_in[23];
    const float* c2_m = (const float*)d_in[24];
    const float* c2_v = (const float*)d_in[25];
    float* out = (float*)d_out;
    char* ws = (char*)d_ws;

    // layout (bytes), total 69,337,344 (<= proven-safe 70,778,880):
    //   Xc   @ 0           (33,554,432)  live: xprep .. k_merge; Aw5 aliases after
    //   regB @ 33,554,432  (33,554,432)  O1 @+0, O2 @+16M (dead after reduce);
    //                                    Rc @+0 aliases both
    //   Aw4  @ 67,108,864  (131,072)
    //   cmax @ 67,239,936  (262,144)
    //   rmax @ 67,502,080  (262,144)
    //   regE @ 67,764,224  (1,572,864)   Aw1/Aw2 then U/V alias
    //   zbuf @ 69,337,088  (256)
    __hip_bfloat16* Xc   = (__hip_bfloat16*)ws;
    char* regB = ws + 33554432;
    __hip_bfloat16* O1   = (__hip_bfloat16*)regB;
    __hip_bfloat16* O2   = (__hip_bfloat16*)(regB + 16777216);
    __hip_bfloat16* Rc   = (__hip_bfloat16*)regB;
    __hip_bfloat16* Aw4  = (__hip_bfloat16*)(ws + 67108864);
    float*          cmax = (float*)(ws + 67239936);
    float*          rmax = (float*)(ws + 67502080);
    char* regE = ws + 67764224;
    __hip_bfloat16* Aw1  = (__hip_bfloat16*)regE;
    __hip_bfloat16* Aw2  = (__hip_bfloat16*)(regE + 589824);
    __hip_bfloat16* Ubuf = (__hip_bfloat16*)regE;
    __hip_bfloat16* Vbuf = (__hip_bfloat16*)(regE + 786432);
    float*          zbuf = (float*)(ws + 69337088);
    __hip_bfloat16* Aw5  = (__hip_bfloat16*)ws;   // aliases Xc, written post-merge

    hipMemsetAsync(zbuf, 0, 256, stream);
    k_xprep<<<dim3(128, 4), 256, 0, stream>>>(x, Xc);
    k_wprep<<<dim3(128), 256, 0, stream>>>(p1_w, Aw1);
    k_wprep<<<dim3(128), 256, 0, stream>>>(p2_w, Aw2);
    k_wprep1<<<dim3(256), 256, 0, stream>>>(c1_w, Aw4);

    k_conv3<<<dim3(128, 1, 4), 256, 0, stream>>>(
        Xc, Aw1, zbuf, p1_g, p1_b, p1_m, p1_v, O1, CMID, 1);
    k_conv3<<<dim3(128, 1, 4), 256, 0, stream>>>(
        Xc, Aw2, zbuf, p2_g, p2_b, p2_m, p2_v, O2, CMID, 1);

    k_reduce<<<dim3(512), 128, 0, stream>>>(O1, O2, cmax, rmax);
    k_uv<<<dim3(256, 4, 2), 128, 0, stream>>>(p_w, cmax, rmax, Ubuf, Vbuf);

    k_merge_mfma<<<dim3(128, 2, 4), 256, 0, stream>>>(
        Xc, Aw4, Ubuf, Vbuf, p_g, p_b, p_m, p_v,
        c1_g, c1_b, c1_m, c1_v, Rc);

    k_wprep<<<dim3(256), 256, 0, stream>>>(c2_w, Aw5);   // Xc dead now
    k_conv3<<<dim3(128, 2, 4), 256, 0, stream>>>(
        Rc, Aw5, zbuf, c2_g, c2_b, c2_m, c2_v, out, CDIM, 0);
}

// Round 5
// 425.265 us; speedup vs baseline: 14.7826x; 1.0203x over previous
//
#include <hip/hip_runtime.h>
#include <hip/hip_bf16.h>
#include <math.h>

// pool_cross on MI355X — round 5: fuse pools into conv epilogues (atomicMax),
// kill O1/O2 round-trip + k_reduce, single-pass xprep, LDS U-tile in merge,
// one wprep kernel, one memset. Conv MFMA core identical to round 4 (42% MfmaUtil).
//
// pool algebra (verified): bottom(top(a)) = colmax bcast, right(left(a)) =
// rowmax bcast; merge conv input is rank-1 -> 1-D k_uv decomposition.
// Pool maxes via atomicMax on fp32 bit-patterns (valid: all values >= 0 post-relu).

constexpr int NB   = 4;
constexpr int CDIM = 256;
constexpr int CMID = 128;
constexpr int HS   = 128;
constexpr int WS   = 128;
constexpr float EPS = 1e-5f;

typedef __bf16 bf16x8 __attribute__((ext_vector_type(8)));
typedef float  f32x4  __attribute__((ext_vector_type(4)));

#define AS1 __attribute__((address_space(1)))
#define AS3 __attribute__((address_space(3)))

__device__ __forceinline__ void load16_lds(const void* gsrc, void* ldst) {
    __builtin_amdgcn_global_load_lds((const AS1 unsigned int*)gsrc,
                                     (AS3 unsigned int*)ldst, 16, 0, 0);
}

// ---------------------------------------------------------------------------
// P0: x[b][ci][y][x] fp32 -> Xc[b][y][x][ci] bf16. Single pass, 512 threads.
__global__ __launch_bounds__(512) void k_xprep(const float* __restrict__ xin,
                                               __hip_bfloat16* __restrict__ Xc)
{
    const int y = blockIdx.x;
    const int b = blockIdx.y;
    const int t = threadIdx.x;
    __shared__ __hip_bfloat16 lds[128 * 264];   // [x][ci], ci-dim padded to 264
#pragma unroll
    for (int k = 0; k < 16; ++k) {
        int idx = t + k * 512;            // 0..8191
        int ci = idx >> 5, x4 = idx & 31;
        f32x4 v = *(const f32x4*)(xin + (((size_t)b * CDIM + ci) * HS + y) * WS + x4 * 4);
#pragma unroll
        for (int j = 0; j < 4; ++j)
            lds[(x4 * 4 + j) * 264 + ci] = __float2bfloat16(v[j]);
    }
    __syncthreads();
#pragma unroll
    for (int k = 0; k < 8; ++k) {
        int i = t + k * 512;              // 0..4095 chunks of 16B
        int x = i >> 5, c8 = i & 31;
        bf16x8 vv = *(const bf16x8*)(lds + x * 264 + c8 * 8);
        *(bf16x8*)(Xc + ((size_t)(b * 128 + y) * 128 + x) * 256 + c8 * 8) = vv;
    }
}

// ---------------------------------------------------------------------------
// All weight preps in one kernel.
// blocks 0..127: Aw1 <- p1_w; 128..255: Aw2 <- p2_w; 256..511: Aw5 <- c2_w;
// 512..639: Aw4 <- c1_w (1x1).
__global__ __launch_bounds__(256) void k_wprep_all(
    const float* __restrict__ p1w, const float* __restrict__ p2w,
    const float* __restrict__ c2w, const float* __restrict__ c1w,
    __hip_bfloat16* __restrict__ Aw1, __hip_bfloat16* __restrict__ Aw2,
    __hip_bfloat16* __restrict__ Aw5, __hip_bfloat16* __restrict__ Aw4)
{
    const int bid = blockIdx.x;
    const int t   = threadIdx.x;
    if (bid < 512) {
        const float* W; __hip_bfloat16* A; int co;
        if (bid < 128)      { W = p1w; A = Aw1; co = bid; }
        else if (bid < 256) { W = p2w; A = Aw2; co = bid - 128; }
        else                { W = c2w; A = Aw5; co = bid - 256; }
#pragma unroll
        for (int tap = 0; tap < 9; ++tap)
            A[(size_t)co * 2304 + tap * 256 + t] =
                __float2bfloat16(W[((size_t)co * CDIM + t) * 9 + tap]);
    } else {
        int base = (bid - 512) * 512 + t;
        Aw4[base]       = __float2bfloat16(c1w[base]);
        Aw4[base + 256] = __float2bfloat16(c1w[base + 256]);
    }
}

// ---------------------------------------------------------------------------
// Conv3x3 implicit GEMM (round-4 core). MODE 0: fp32 NCHW store (outp=float*).
// MODE 1: colmax atomics (outp=unsigned* cmax[b][co][x]). MODE 2: rowmax
// atomics with LDS pre-reduce (outp=unsigned* rmax[b][co][y]).
template<int MODE>
__global__ __launch_bounds__(256, 2) void k_conv3(
    const __hip_bfloat16* __restrict__ Xc,   // [b][128][128][256] (or Rc)
    const __hip_bfloat16* __restrict__ Aw,   // [CO][2304]
    const float* __restrict__ zbuf,          // >=256B of zeros
    const float* __restrict__ gg, const float* __restrict__ bbp,
    const float* __restrict__ mmp, const float* __restrict__ vvp,
    void* __restrict__ outp, int CO)
{
    const int y   = blockIdx.x;
    const int co0 = blockIdx.y * 128;
    const int b   = blockIdx.z;

    __shared__ __hip_bfloat16 smem[514 * 64];   // 514 rows x 128 B
    __shared__ float s_sc[128], s_sh[128];
    __shared__ unsigned s_red[128];
    char* smb = (char*)smem;

    const int t    = threadIdx.x;
    const int lane = t & 63;
    const int w    = t >> 6;
    const int ml   = lane & 15;
    const int q    = lane >> 4;
    const int mbase = (w >> 1) * 64;
    const int nbase = (w & 1) * 64;

    if (t < 128) {
        int co = co0 + t;
        float iv = rsqrtf(vvp[co] + EPS);
        float sc = gg[co] * iv;
        s_sc[t] = sc;
        s_sh[t] = bbp[co] - mmp[co] * sc;
        if (MODE == 2) s_red[t] = 0u;
    }

    f32x4 acc[4][4];
#pragma unroll
    for (int mt = 0; mt < 4; ++mt)
#pragma unroll
        for (int nt = 0; nt < 4; ++nt)
            acc[mt][nt] = (f32x4){0.f, 0.f, 0.f, 0.f};

#pragma unroll 1
    for (int ky = 0; ky < 3; ++ky) {
        const int ydata = y + ky - 1;
        if ((unsigned)ydata >= 128u) continue;     // zero-padded tap row
        const __hip_bfloat16* arow = Aw + (size_t)co0 * 2304 + (3 * ky) * 256;
        const __hip_bfloat16* brow = Xc + (size_t)(b * 128 + ydata) * 128 * 256;
#pragma unroll 1
        for (int cih = 0; cih < 4; ++cih) {
#pragma unroll
            for (int p = 0; p < 17; ++p) {
                int i = t + p * 256;
                if (i < 4112) {
                    int row = i >> 3;
                    int cl  = (i & 7) ^ (row & 7);
                    const __hip_bfloat16* src;
                    if (row < 384) {
                        int j    = row >> 7;
                        int co_l = row & 127;
                        src = arow + (size_t)co_l * 2304 + j * 256 + cih * 64 + cl * 8;
                    } else {
                        int gx = (row - 384) - 1;
                        src = ((unsigned)gx < 128u)
                            ? brow + (size_t)gx * 256 + cih * 64 + cl * 8
                            : (const __hip_bfloat16*)((const char*)zbuf + cl * 16);
                    }
                    load16_lds(src, smb + (size_t)i * 16);
                }
            }
            __syncthreads();
#pragma unroll
            for (int j = 0; j < 3; ++j) {
#pragma unroll
                for (int s = 0; s < 2; ++s) {
                    bf16x8 af[4], bfv[4];
#pragma unroll
                    for (int mt = 0; mt < 4; ++mt) {
                        const int ra = j * 128 + mbase + mt * 16 + ml;
                        const int coff = ((s * 4 + q) ^ (ra & 7)) * 16;
                        af[mt] = *(const bf16x8*)(smb + (size_t)ra * 128 + coff);
                    }
#pragma unroll
                    for (int nt = 0; nt < 4; ++nt) {
                        const int rb = 384 + nbase + nt * 16 + ml + j;
                        const int coff = ((s * 4 + q) ^ (rb & 7)) * 16;
                        bfv[nt] = *(const bf16x8*)(smb + (size_t)rb * 128 + coff);
                    }
#pragma unroll
                    for (int mt = 0; mt < 4; ++mt)
#pragma unroll
                        for (int nt = 0; nt < 4; ++nt)
                            acc[mt][nt] = __builtin_amdgcn_mfma_f32_16x16x32_bf16(
                                af[mt], bfv[nt], acc[mt][nt], 0, 0, 0);
                }
            }
            __syncthreads();
        }
    }

    // epilogue. C/D: col(x)=ml, row(co)=q*4+r.
#pragma unroll
    for (int mt = 0; mt < 4; ++mt) {
#pragma unroll
        for (int r = 0; r < 4; ++r) {
            const int col = mbase + mt * 16 + q * 4 + r;
            const float sc = s_sc[col], sh = s_sh[col];
            const int co = co0 + col;
            unsigned rmx = 0u;
#pragma unroll
            for (int nt = 0; nt < 4; ++nt) {
                float v = fmaxf(acc[mt][nt][r] * sc + sh, 0.f);
                const int x = nbase + nt * 16 + ml;
                if (MODE == 0) {
                    ((float*)outp)[(((size_t)b * CO + co) * HS + y) * WS + x] = v;
                } else if (MODE == 1) {
                    atomicMax((unsigned*)outp + ((size_t)(b * 128 + co)) * 128 + x,
                              __float_as_uint(v));
                } else {
                    rmx = max(rmx, __float_as_uint(v));
                }
            }
            if (MODE == 2) atomicMax(&s_red[col], rmx);
        }
    }
    if (MODE == 2) {
        __syncthreads();
        if (t < 128)
            atomicMax((unsigned*)outp + ((size_t)(b * 128 + t)) * 128 + y, s_red[t]);
    }
}

// ---------------------------------------------------------------------------
// K3: 1-D decomposition of the merge conv -> U,V (bf16 out).
__global__ __launch_bounds__(128) void k_uv(
    const float* __restrict__ pw, const float* __restrict__ cm,
    const float* __restrict__ rm,
    __hip_bfloat16* __restrict__ U, __hip_bfloat16* __restrict__ V)
{
    const int co   = blockIdx.x;
    const int b    = blockIdx.y;
    const int mode = blockIdx.z;
    const int p    = threadIdx.x;
    float acc0 = 0.f, acc1 = 0.f, acc2 = 0.f;
    const float* base = (mode == 0) ? cm : rm;
    for (int ci = 0; ci < CMID; ++ci) {
        const float* w9 = pw + (co * CMID + ci) * 9;
        float s0[3], s1[3], s2[3];
        if (mode == 0) {
#pragma unroll
            for (int k = 0; k < 3; ++k) {
                float a = w9[k], qq = w9[3 + k], r = w9[6 + k];
                s0[k] = qq + r; s1[k] = a + qq + r; s2[k] = a + qq;
            }
        } else {
#pragma unroll
            for (int k = 0; k < 3; ++k) {
                float a = w9[k*3 + 0], qq = w9[k*3 + 1], r = w9[k*3 + 2];
                s0[k] = qq + r; s1[k] = a + qq + r; s2[k] = a + qq;
            }
        }
        const float* v = base + (b * CMID + ci) * 128;
#pragma unroll
        for (int k = 0; k < 3; ++k) {
            int pos = p + k - 1;
            if ((unsigned)pos < 128u) {
                float vv = v[pos];
                acc0 += s0[k] * vv; acc1 += s1[k] * vv; acc2 += s2[k] * vv;
            }
        }
    }
    __hip_bfloat16* dst = (mode == 0) ? U : V;
    dst[((0 * NB + b) * CDIM + co) * 128 + p] = __float2bfloat16(acc0);
    dst[((1 * NB + b) * CDIM + co) * 128 + p] = __float2bfloat16(acc1);
    dst[((2 * NB + b) * CDIM + co) * 128 + p] = __float2bfloat16(acc2);
}

// ---------------------------------------------------------------------------
// K4: merge as MFMA GEMM. Rc[b][y][x][co] = relu(psc*(U+V)+psh + csc*xw+csh).
// U tile staged into (reused) LDS for the epilogue.
__global__ __launch_bounds__(256, 3) void k_merge_mfma(
    const __hip_bfloat16* __restrict__ Xc, const __hip_bfloat16* __restrict__ Aw4,
    const __hip_bfloat16* __restrict__ U, const __hip_bfloat16* __restrict__ V,
    const float* __restrict__ pg, const float* __restrict__ pb,
    const float* __restrict__ pm, const float* __restrict__ pv,
    const float* __restrict__ cg, const float* __restrict__ cb,
    const float* __restrict__ cmn, const float* __restrict__ cv,
    __hip_bfloat16* __restrict__ Rc)
{
    const int y   = blockIdx.x;
    const int cot = blockIdx.y;
    const int b   = blockIdx.z;
    const int co0 = cot * 128;
    __shared__ __hip_bfloat16 smem[256 * 64];   // GEMM staging, then U tile
    __shared__ float s_psc[128], s_psh[128], s_csc[128], s_csh[128];
    __shared__ float s_v0[128], s_vm[128], s_v1[128];
    char* smb = (char*)smem;
    const int t = threadIdx.x, lane = t & 63, w = t >> 6;
    const int ml = lane & 15, q = lane >> 4;
    const int mbase = (w >> 1) * 64, nbase = (w & 1) * 64;
    const int yc = (y == 0) ? 0 : ((y == HS - 1) ? 2 : 1);

    if (t < 128) {
        int co = co0 + t;
        float iv = rsqrtf(pv[co] + EPS);
        float psc = pg[co] * iv;
        s_psc[t] = psc;
        s_psh[t] = pb[co] - pm[co] * psc;
        float iv2 = rsqrtf(cv[co] + EPS);
        float csc = cg[co] * iv2;
        s_csc[t] = csc;
        s_csh[t] = cb[co] - cmn[co] * csc;
        const size_t vb = ((size_t)b * CDIM + co) * 128 + y;
        const size_t cstr = (size_t)NB * CDIM * 128;
        s_v0[t] = __bfloat162float(V[vb]);
        s_vm[t] = __bfloat162float(V[cstr + vb]);
        s_v1[t] = __bfloat162float(V[2 * cstr + vb]);
    }

    f32x4 acc[4][4];
#pragma unroll
    for (int mt = 0; mt < 4; ++mt)
#pragma unroll
        for (int nt = 0; nt < 4; ++nt)
            acc[mt][nt] = (f32x4){0.f, 0.f, 0.f, 0.f};

    const __hip_bfloat16* brow = Xc + (size_t)(b * 128 + y) * 128 * 256;
#pragma unroll 1
    for (int ks = 0; ks < 4; ++ks) {
        const __hip_bfloat16* ab = Aw4 + (size_t)co0 * 256 + ks * 64;
        const __hip_bfloat16* bb = brow + ks * 64;
#pragma unroll
        for (int p = 0; p < 8; ++p) {
            int i   = t + p * 256;
            int row = i >> 3;
            int c   = (i & 7) ^ (row & 7);
            const __hip_bfloat16* src = (row < 128)
                ? ab + (size_t)row * 256 + c * 8
                : bb + (size_t)(row - 128) * 256 + c * 8;
            load16_lds(src, smb + (size_t)i * 16);
        }
        __syncthreads();
#pragma unroll
        for (int s = 0; s < 2; ++s) {
            const int coff = ((s * 4 + q) ^ (ml & 7)) * 16;
            bf16x8 af[4], bfv[4];
#pragma unroll
            for (int mt = 0; mt < 4; ++mt)
                af[mt] = *(const bf16x8*)(smb + (size_t)(mbase + mt * 16 + ml) * 128 + coff);
#pragma unroll
            for (int nt = 0; nt < 4; ++nt)
                bfv[nt] = *(const bf16x8*)(smb + (size_t)(128 + nbase + nt * 16 + ml) * 128 + coff);
#pragma unroll
            for (int mt = 0; mt < 4; ++mt)
#pragma unroll
                for (int nt = 0; nt < 4; ++nt)
                    acc[mt][nt] = __builtin_amdgcn_mfma_f32_16x16x32_bf16(
                        af[mt], bfv[nt], acc[mt][nt], 0, 0, 0);
        }
        __syncthreads();
    }

    // stage U tile (128co x 128x bf16 = 32 KB, contiguous) into smem
    const __hip_bfloat16* Ub = U + ((size_t)(yc * NB + b) * CDIM + co0) * 128;
#pragma unroll
    for (int p = 0; p < 8; ++p) {
        int i = t + p * 256;
        load16_lds(Ub + (size_t)i * 8, smb + (size_t)i * 16);
    }
    __syncthreads();

#pragma unroll
    for (int mt = 0; mt < 4; ++mt) {
#pragma unroll
        for (int nt = 0; nt < 4; ++nt) {
            const int x = nbase + nt * 16 + ml;
            unsigned long long pk = 0;
#pragma unroll
            for (int r = 0; r < 4; ++r) {
                const int col = mbase + mt * 16 + q * 4 + r;
                float u  = __bfloat162float(smem[col * 128 + x]);
                float vt = (x == 0) ? s_v0[col] : ((x == WS - 1) ? s_v1[col] : s_vm[col]);
                float val = fmaxf((u + vt) * s_psc[col] + s_psh[col]
                                  + acc[mt][nt][r] * s_csc[col] + s_csh[col], 0.f);
                __hip_bfloat16 hb = __float2bfloat16(val);
                unsigned short bits;
                __builtin_memcpy(&bits, &hb, 2);
                pk |= (unsigned long long)bits << (16 * r);
            }
            *(unsigned long long*)((char*)Rc +
                ((size_t)((b * 128 + y) * 128 + x) * 256 + co0 + mbase + mt * 16 + q * 4) * 2) = pk;
        }
    }
}

// ---------------------------------------------------------------------------
extern "C" void kernel_launch(void* const* d_in, const int* in_sizes, int n_in,
                              void* d_out, int out_size, void* d_ws, size_t ws_size,
                              hipStream_t stream)
{
    (void)in_sizes; (void)n_in; (void)out_size; (void)ws_size;
    const float* x    = (const float*)d_in[0];
    const float* p1_w = (const float*)d_in[1];
    const float* p1_g = (const float*)d_in[2];
    const float* p1_b = (const float*)d_in[3];
    const float* p1_m = (const float*)d_in[4];
    const float* p1_v = (const float*)d_in[5];
    const float* p2_w = (const float*)d_in[6];
    const float* p2_g = (const float*)d_in[7];
    const float* p2_b = (const float*)d_in[8];
    const float* p2_m = (const float*)d_in[9];
    const float* p2_v = (const float*)d_in[10];
    const float* p_w  = (const float*)d_in[11];
    const float* p_g  = (const float*)d_in[12];
    const float* p_b  = (const float*)d_in[13];
    const float* p_m  = (const float*)d_in[14];
    const float* p_v  = (const float*)d_in[15];
    const float* c1_w = (const float*)d_in[16];
    const float* c1_g = (const float*)d_in[17];
    const float* c1_b = (const float*)d_in[18];
    const float* c1_m = (const float*)d_in[19];
    const float* c1_v = (const float*)d_in[20];
    const float* c2_w = (const float*)d_in[21];
    const float* c2_g = (const float*)d_in[22];
    const float* c2_b = (const float*)d_in[23];
    const float* c2_m = (const float*)d_in[24];
    const float* c2_v = (const float*)d_in[25];
    float* out = (float*)d_out;
    char* ws = (char*)d_ws;

    // layout (bytes), total 70,516,992 (<= proven-safe 70,778,880):
    //   Xc    @ 0           (33,554,432)  live xprep..merge
    //   Rc    @ 33,554,432  (33,554,432)  live merge..conv5
    //   U     @ 67,108,864  (786,432)  \ alias Aw1 (589,824 @67,108,864) and
    //   V     @ 67,895,296  (786,432)  / Aw2 (589,824 @67,698,688) — dead pre-uv
    //   Aw5   @ 68,681,728  (1,179,648)
    //   Aw4   @ 69,861,376  (131,072)
    //   cmaxU @ 69,992,448  (262,144)  \
    //   rmaxU @ 70,254,592  (262,144)   > one memset region (524,544)
    //   zbuf  @ 70,516,736  (256)      /
    __hip_bfloat16* Xc   = (__hip_bfloat16*)ws;
    __hip_bfloat16* Rc   = (__hip_bfloat16*)(ws + 33554432);
    __hip_bfloat16* Ubuf = (__hip_bfloat16*)(ws + 67108864);
    __hip_bfloat16* Vbuf = (__hip_bfloat16*)(ws + 67895296);
    __hip_bfloat16* Aw1  = (__hip_bfloat16*)(ws + 67108864);
    __hip_bfloat16* Aw2  = (__hip_bfloat16*)(ws + 67698688);
    __hip_bfloat16* Aw5  = (__hip_bfloat16*)(ws + 68681728);
    __hip_bfloat16* Aw4  = (__hip_bfloat16*)(ws + 69861376);
    unsigned*       cmaxU = (unsigned*)(ws + 69992448);
    unsigned*       rmaxU = (unsigned*)(ws + 70254592);
    float*          zbuf  = (float*)(ws + 70516736);

    hipMemsetAsync(ws + 69992448, 0, 524544, stream);
    k_xprep<<<dim3(128, 4), 512, 0, stream>>>(x, Xc);
    k_wprep_all<<<dim3(640), 256, 0, stream>>>(
        p1_w, p2_w, c2_w, c1_w, Aw1, Aw2, Aw5, Aw4);

    k_conv3<1><<<dim3(128, 1, 4), 256, 0, stream>>>(
        Xc, Aw1, zbuf, p1_g, p1_b, p1_m, p1_v, cmaxU, CMID);
    k_conv3<2><<<dim3(128, 1, 4), 256, 0, stream>>>(
        Xc, Aw2, zbuf, p2_g, p2_b, p2_m, p2_v, rmaxU, CMID);

    k_uv<<<dim3(256, 4, 2), 128, 0, stream>>>(
        p_w, (const float*)cmaxU, (const float*)rmaxU, Ubuf, Vbuf);

    k_merge_mfma<<<dim3(128, 2, 4), 256, 0, stream>>>(
        Xc, Aw4, Ubuf, Vbuf, p_g, p_b, p_m, p_v,
        c1_g, c1_b, c1_m, c1_v, Rc);

    k_conv3<0><<<dim3(128, 2, 4), 256, 0, stream>>>(
        Rc, Aw5, zbuf, c2_g, c2_b, c2_m, c2_v, out, CDIM);
}

// Round 6
// 392.705 us; speedup vs baseline: 16.0083x; 1.0829x over previous
//
#include <hip/hip_runtime.h>
#include <hip/hip_bf16.h>
#include <math.h>

// pool_cross on MI355X — round 6: conv core v2.
// 2-row y-tiles (A-fragments shared across rows), 32-ci staging chunks with
// 64-B LDS rows (bank-uniform ds_read_b128, no swizzle), K1+K2 fused into one
// dispatch. Staged bytes/output 60->36, LDS reads 0.5->0.375 per MFMA.
//
// pool algebra (verified): bottom(top(a)) = colmax bcast, right(left(a)) =
// rowmax bcast; merge conv input is rank-1 -> 1-D k_uv decomposition.
// Pool maxes via atomicMax on fp32 bits (valid: values >= 0 post-relu).

constexpr int NB   = 4;
constexpr int CDIM = 256;
constexpr int CMID = 128;
constexpr int HS   = 128;
constexpr int WS   = 128;
constexpr float EPS = 1e-5f;

typedef __bf16 bf16x8 __attribute__((ext_vector_type(8)));
typedef float  f32x4  __attribute__((ext_vector_type(4)));

#define AS1 __attribute__((address_space(1)))
#define AS3 __attribute__((address_space(3)))

__device__ __forceinline__ void load16_lds(const void* gsrc, void* ldst) {
    __builtin_amdgcn_global_load_lds((const AS1 unsigned int*)gsrc,
                                     (AS3 unsigned int*)ldst, 16, 0, 0);
}

// ---------------------------------------------------------------------------
// P0: x[b][ci][y][x] fp32 -> Xc[b][y][x][ci] bf16. Single pass, 512 threads.
__global__ __launch_bounds__(512) void k_xprep(const float* __restrict__ xin,
                                               __hip_bfloat16* __restrict__ Xc)
{
    const int y = blockIdx.x;
    const int b = blockIdx.y;
    const int t = threadIdx.x;
    __shared__ __hip_bfloat16 lds[128 * 264];   // [x][ci], ci-dim padded to 264
#pragma unroll
    for (int k = 0; k < 16; ++k) {
        int idx = t + k * 512;            // 0..8191
        int ci = idx >> 5, x4 = idx & 31;
        f32x4 v = *(const f32x4*)(xin + (((size_t)b * CDIM + ci) * HS + y) * WS + x4 * 4);
#pragma unroll
        for (int j = 0; j < 4; ++j)
            lds[(x4 * 4 + j) * 264 + ci] = __float2bfloat16(v[j]);
    }
    __syncthreads();
#pragma unroll
    for (int k = 0; k < 8; ++k) {
        int i = t + k * 512;              // 0..4095 chunks of 16B
        int x = i >> 5, c8 = i & 31;
        bf16x8 vv = *(const bf16x8*)(lds + x * 264 + c8 * 8);
        *(bf16x8*)(Xc + ((size_t)(b * 128 + y) * 128 + x) * 256 + c8 * 8) = vv;
    }
}

// ---------------------------------------------------------------------------
// All weight preps in one kernel.
__global__ __launch_bounds__(256) void k_wprep_all(
    const float* __restrict__ p1w, const float* __restrict__ p2w,
    const float* __restrict__ c2w, const float* __restrict__ c1w,
    __hip_bfloat16* __restrict__ Aw1, __hip_bfloat16* __restrict__ Aw2,
    __hip_bfloat16* __restrict__ Aw5, __hip_bfloat16* __restrict__ Aw4)
{
    const int bid = blockIdx.x;
    const int t   = threadIdx.x;
    if (bid < 512) {
        const float* W; __hip_bfloat16* A; int co;
        if (bid < 128)      { W = p1w; A = Aw1; co = bid; }
        else if (bid < 256) { W = p2w; A = Aw2; co = bid - 128; }
        else                { W = c2w; A = Aw5; co = bid - 256; }
#pragma unroll
        for (int tap = 0; tap < 9; ++tap)
            A[(size_t)co * 2304 + tap * 256 + t] =
                __float2bfloat16(W[((size_t)co * CDIM + t) * 9 + tap]);
    } else {
        int base = (bid - 512) * 512 + t;
        Aw4[base]       = __float2bfloat16(c1w[base]);
        Aw4[base + 256] = __float2bfloat16(c1w[base + 256]);
    }
}

// ---------------------------------------------------------------------------
// Conv3x3 implicit GEMM v2. Tile: 2 y-rows x 128 co x 128 x. 256 threads.
// Per (ky, 32-ci chunk): stage A (3kx x 128co, 64B rows) + B (2 haloed x-rows),
// then 3 kx x (A-frags shared over 2 y rows) x 16 MFMA. LDS rows are 64B;
// 16 consecutive-row b128 reads are bank-uniform -> no swizzle needed.
// MODE 0: plain fp32 NCHW store (K5). MODE 1: fused branch kernel (K1+K2):
// blockIdx.y==0 -> colmax atomics (Aw1/bn1), ==1 -> rowmax (Aw2/bn2).
template<int MODE>
__global__ __launch_bounds__(256, 2) void k_conv3(
    const __hip_bfloat16* __restrict__ Xc,
    const __hip_bfloat16* __restrict__ AwA, const __hip_bfloat16* __restrict__ AwB,
    const float* __restrict__ zbuf,
    const float* __restrict__ g1, const float* __restrict__ b1,
    const float* __restrict__ m1, const float* __restrict__ v1,
    const float* __restrict__ g2, const float* __restrict__ b2,
    const float* __restrict__ m2, const float* __restrict__ v2,
    float* __restrict__ out0, unsigned* __restrict__ cmax,
    unsigned* __restrict__ rmax, int CO)
{
    const int y0     = blockIdx.x * 2;
    const int branch = blockIdx.y;              // MODE1: branch; MODE0: co-tile
    const int b      = blockIdx.z;
    const int co0    = (MODE == 0) ? branch * 128 : 0;

    const __hip_bfloat16* Aw = (MODE == 1 && branch) ? AwB : AwA;
    const float* gg  = (MODE == 1 && branch) ? g2 : g1;
    const float* bbp = (MODE == 1 && branch) ? b2 : b1;
    const float* mmp = (MODE == 1 && branch) ? m2 : m1;
    const float* vvp = (MODE == 1 && branch) ? v2 : v1;

    __shared__ __hip_bfloat16 smem[644 * 32];   // 644 rows x 64 B = 41,216 B
    __shared__ float s_sc[128], s_sh[128];
    __shared__ unsigned s_red[2][128];
    char* smb = (char*)smem;

    const int t    = threadIdx.x;
    const int lane = t & 63;
    const int w    = t >> 6;
    const int ml   = lane & 15;
    const int q    = lane >> 4;
    const int mbase = (w >> 1) * 64;
    const int nbase = (w & 1) * 64;

    if (t < 128) {
        int co = co0 + t;
        float iv = rsqrtf(vvp[co] + EPS);
        float sc = gg[co] * iv;
        s_sc[t] = sc;
        s_sh[t] = bbp[co] - mmp[co] * sc;
        if (MODE == 1) { s_red[0][t] = 0u; s_red[1][t] = 0u; }
    }

    f32x4 acc[2][4][4];
#pragma unroll
    for (int yy = 0; yy < 2; ++yy)
#pragma unroll
        for (int mt = 0; mt < 4; ++mt)
#pragma unroll
            for (int nt = 0; nt < 4; ++nt)
                acc[yy][mt][nt] = (f32x4){0.f, 0.f, 0.f, 0.f};

    const __hip_bfloat16* bbase = Xc + (size_t)(b * 128) * 128 * 256;

#pragma unroll 1
    for (int ky = 0; ky < 3; ++ky) {
        const int yd0 = y0 + ky - 1;
        const __hip_bfloat16* arow = Aw + (size_t)co0 * 2304 + (3 * ky) * 256;
#pragma unroll 1
        for (int cih = 0; cih < 8; ++cih) {
            const int cb = cih * 32;
            // ---- stage 2576 x 16B: A rows 0..383 (row=kx*128+co), B rows
            //      384..643 (row=384+yy*130+xi, gx=xi-1) ----
#pragma unroll
            for (int p = 0; p < 11; ++p) {
                int i = t + p * 256;
                if (i < 2576) {
                    int row = i >> 2, c = i & 3;
                    const __hip_bfloat16* src;
                    if (row < 384) {
                        int j = row >> 7, col = row & 127;
                        src = arow + (size_t)col * 2304 + j * 256 + cb + c * 8;
                    } else {
                        int rbi = row - 384;
                        int yy  = rbi >= 130;
                        int xi  = rbi - 130 * yy;
                        int gy  = yd0 + yy, gx = xi - 1;
                        src = ((unsigned)gy < 128u && (unsigned)gx < 128u)
                            ? bbase + ((size_t)(gy * 128 + gx)) * 256 + cb + c * 8
                            : (const __hip_bfloat16*)((const char*)zbuf + c * 16);
                    }
                    load16_lds(src, smb + (size_t)i * 16);
                }
            }
            __syncthreads();
            // ---- 3 kx, A-frag shared across 2 y rows ----
#pragma unroll
            for (int j = 0; j < 3; ++j) {
                bf16x8 af[4];
#pragma unroll
                for (int mt = 0; mt < 4; ++mt)
                    af[mt] = *(const bf16x8*)(smb +
                        (size_t)(j * 128 + mbase + mt * 16 + ml) * 64 + q * 16);
#pragma unroll
                for (int yy = 0; yy < 2; ++yy) {
                    bf16x8 bfv[4];
#pragma unroll
                    for (int nt = 0; nt < 4; ++nt)
                        bfv[nt] = *(const bf16x8*)(smb +
                            (size_t)(384 + yy * 130 + nbase + nt * 16 + ml + j) * 64 + q * 16);
#pragma unroll
                    for (int mt = 0; mt < 4; ++mt)
#pragma unroll
                        for (int nt = 0; nt < 4; ++nt)
                            acc[yy][mt][nt] = __builtin_amdgcn_mfma_f32_16x16x32_bf16(
                                af[mt], bfv[nt], acc[yy][mt][nt], 0, 0, 0);
                }
            }
            __syncthreads();
        }
    }

    // epilogue. C/D: col(x)=ml, row(co)=q*4+r.
#pragma unroll
    for (int mt = 0; mt < 4; ++mt) {
#pragma unroll
        for (int r = 0; r < 4; ++r) {
            const int col = mbase + mt * 16 + q * 4 + r;
            const float sc = s_sc[col], sh = s_sh[col];
            const int co = co0 + col;
            unsigned rmx0 = 0u, rmx1 = 0u;
#pragma unroll
            for (int nt = 0; nt < 4; ++nt) {
                float va = fmaxf(acc[0][mt][nt][r] * sc + sh, 0.f);
                float vb = fmaxf(acc[1][mt][nt][r] * sc + sh, 0.f);
                const int x = nbase + nt * 16 + ml;
                if (MODE == 0) {
                    out0[(((size_t)b * CO + co) * HS + y0)     * WS + x] = va;
                    out0[(((size_t)b * CO + co) * HS + y0 + 1) * WS + x] = vb;
                } else if (branch == 0) {
                    atomicMax(cmax + ((size_t)(b * 128 + co)) * 128 + x,
                              __float_as_uint(fmaxf(va, vb)));
                } else {
                    rmx0 = max(rmx0, __float_as_uint(va));
                    rmx1 = max(rmx1, __float_as_uint(vb));
                }
            }
            if (MODE == 1 && branch == 1) {
                atomicMax(&s_red[0][col], rmx0);
                atomicMax(&s_red[1][col], rmx1);
            }
        }
    }
    if (MODE == 1 && branch == 1) {
        __syncthreads();
        if (t < 128) {
            atomicMax(rmax + ((size_t)(b * 128 + t)) * 128 + y0,     s_red[0][t]);
            atomicMax(rmax + ((size_t)(b * 128 + t)) * 128 + y0 + 1, s_red[1][t]);
        }
    }
}

// ---------------------------------------------------------------------------
// K3: 1-D decomposition of the merge conv -> U,V (bf16 out).
__global__ __launch_bounds__(128) void k_uv(
    const float* __restrict__ pw, const float* __restrict__ cm,
    const float* __restrict__ rm,
    __hip_bfloat16* __restrict__ U, __hip_bfloat16* __restrict__ V)
{
    const int co   = blockIdx.x;
    const int b    = blockIdx.y;
    const int mode = blockIdx.z;
    const int p    = threadIdx.x;
    float acc0 = 0.f, acc1 = 0.f, acc2 = 0.f;
    const float* base = (mode == 0) ? cm : rm;
    for (int ci = 0; ci < CMID; ++ci) {
        const float* w9 = pw + (co * CMID + ci) * 9;
        float s0[3], s1[3], s2[3];
        if (mode == 0) {
#pragma unroll
            for (int k = 0; k < 3; ++k) {
                float a = w9[k], qq = w9[3 + k], r = w9[6 + k];
                s0[k] = qq + r; s1[k] = a + qq + r; s2[k] = a + qq;
            }
        } else {
#pragma unroll
            for (int k = 0; k < 3; ++k) {
                float a = w9[k*3 + 0], qq = w9[k*3 + 1], r = w9[k*3 + 2];
                s0[k] = qq + r; s1[k] = a + qq + r; s2[k] = a + qq;
            }
        }
        const float* v = base + (b * CMID + ci) * 128;
#pragma unroll
        for (int k = 0; k < 3; ++k) {
            int pos = p + k - 1;
            if ((unsigned)pos < 128u) {
                float vv = v[pos];
                acc0 += s0[k] * vv; acc1 += s1[k] * vv; acc2 += s2[k] * vv;
            }
        }
    }
    __hip_bfloat16* dst = (mode == 0) ? U : V;
    dst[((0 * NB + b) * CDIM + co) * 128 + p] = __float2bfloat16(acc0);
    dst[((1 * NB + b) * CDIM + co) * 128 + p] = __float2bfloat16(acc1);
    dst[((2 * NB + b) * CDIM + co) * 128 + p] = __float2bfloat16(acc2);
}

// ---------------------------------------------------------------------------
// K4: merge as MFMA GEMM. Rc[b][y][x][co] = relu(psc*(U+V)+psh + csc*xw+csh).
__global__ __launch_bounds__(256, 3) void k_merge_mfma(
    const __hip_bfloat16* __restrict__ Xc, const __hip_bfloat16* __restrict__ Aw4,
    const __hip_bfloat16* __restrict__ U, const __hip_bfloat16* __restrict__ V,
    const float* __restrict__ pg, const float* __restrict__ pb,
    const float* __restrict__ pm, const float* __restrict__ pv,
    const float* __restrict__ cg, const float* __restrict__ cb,
    const float* __restrict__ cmn, const float* __restrict__ cv,
    __hip_bfloat16* __restrict__ Rc)
{
    const int y   = blockIdx.x;
    const int cot = blockIdx.y;
    const int b   = blockIdx.z;
    const int co0 = cot * 128;
    __shared__ __hip_bfloat16 smem[256 * 64];
    __shared__ float s_psc[128], s_psh[128], s_csc[128], s_csh[128];
    __shared__ float s_v0[128], s_vm[128], s_v1[128];
    char* smb = (char*)smem;
    const int t = threadIdx.x, lane = t & 63, w = t >> 6;
    const int ml = lane & 15, q = lane >> 4;
    const int mbase = (w >> 1) * 64, nbase = (w & 1) * 64;
    const int yc = (y == 0) ? 0 : ((y == HS - 1) ? 2 : 1);

    if (t < 128) {
        int co = co0 + t;
        float iv = rsqrtf(pv[co] + EPS);
        float psc = pg[co] * iv;
        s_psc[t] = psc;
        s_psh[t] = pb[co] - pm[co] * psc;
        float iv2 = rsqrtf(cv[co] + EPS);
        float csc = cg[co] * iv2;
        s_csc[t] = csc;
        s_csh[t] = cb[co] - cmn[co] * csc;
        const size_t vb = ((size_t)b * CDIM + co) * 128 + y;
        const size_t cstr = (size_t)NB * CDIM * 128;
        s_v0[t] = __bfloat162float(V[vb]);
        s_vm[t] = __bfloat162float(V[cstr + vb]);
        s_v1[t] = __bfloat162float(V[2 * cstr + vb]);
    }

    f32x4 acc[4][4];
#pragma unroll
    for (int mt = 0; mt < 4; ++mt)
#pragma unroll
        for (int nt = 0; nt < 4; ++nt)
            acc[mt][nt] = (f32x4){0.f, 0.f, 0.f, 0.f};

    const __hip_bfloat16* brow = Xc + (size_t)(b * 128 + y) * 128 * 256;
#pragma unroll 1
    for (int ks = 0; ks < 4; ++ks) {
        const __hip_bfloat16* ab = Aw4 + (size_t)co0 * 256 + ks * 64;
        const __hip_bfloat16* bb = brow + ks * 64;
#pragma unroll
        for (int p = 0; p < 8; ++p) {
            int i   = t + p * 256;
            int row = i >> 3;
            int c   = (i & 7) ^ (row & 7);
            const __hip_bfloat16* src = (row < 128)
                ? ab + (size_t)row * 256 + c * 8
                : bb + (size_t)(row - 128) * 256 + c * 8;
            load16_lds(src, smb + (size_t)i * 16);
        }
        __syncthreads();
#pragma unroll
        for (int s = 0; s < 2; ++s) {
            const int coff = ((s * 4 + q) ^ (ml & 7)) * 16;
            bf16x8 af[4], bfv[4];
#pragma unroll
            for (int mt = 0; mt < 4; ++mt)
                af[mt] = *(const bf16x8*)(smb + (size_t)(mbase + mt * 16 + ml) * 128 + coff);
#pragma unroll
            for (int nt = 0; nt < 4; ++nt)
                bfv[nt] = *(const bf16x8*)(smb + (size_t)(128 + nbase + nt * 16 + ml) * 128 + coff);
#pragma unroll
            for (int mt = 0; mt < 4; ++mt)
#pragma unroll
                for (int nt = 0; nt < 4; ++nt)
                    acc[mt][nt] = __builtin_amdgcn_mfma_f32_16x16x32_bf16(
                        af[mt], bfv[nt], acc[mt][nt], 0, 0, 0);
        }
        __syncthreads();
    }

    const __hip_bfloat16* Ub = U + ((size_t)(yc * NB + b) * CDIM + co0) * 128;
#pragma unroll
    for (int p = 0; p < 8; ++p) {
        int i = t + p * 256;
        load16_lds(Ub + (size_t)i * 8, smb + (size_t)i * 16);
    }
    __syncthreads();

#pragma unroll
    for (int mt = 0; mt < 4; ++mt) {
#pragma unroll
        for (int nt = 0; nt < 4; ++nt) {
            const int x = nbase + nt * 16 + ml;
            unsigned long long pk = 0;
#pragma unroll
            for (int r = 0; r < 4; ++r) {
                const int col = mbase + mt * 16 + q * 4 + r;
                float u  = __bfloat162float(smem[col * 128 + x]);
                float vt = (x == 0) ? s_v0[col] : ((x == WS - 1) ? s_v1[col] : s_vm[col]);
                float val = fmaxf((u + vt) * s_psc[col] + s_psh[col]
                                  + acc[mt][nt][r] * s_csc[col] + s_csh[col], 0.f);
                __hip_bfloat16 hb = __float2bfloat16(val);
                unsigned short bits;
                __builtin_memcpy(&bits, &hb, 2);
                pk |= (unsigned long long)bits << (16 * r);
            }
            *(unsigned long long*)((char*)Rc +
                ((size_t)((b * 128 + y) * 128 + x) * 256 + co0 + mbase + mt * 16 + q * 4) * 2) = pk;
        }
    }
}

// ---------------------------------------------------------------------------
extern "C" void kernel_launch(void* const* d_in, const int* in_sizes, int n_in,
                              void* d_out, int out_size, void* d_ws, size_t ws_size,
                              hipStream_t stream)
{
    (void)in_sizes; (void)n_in; (void)out_size; (void)ws_size;
    const float* x    = (const float*)d_in[0];
    const float* p1_w = (const float*)d_in[1];
    const float* p1_g = (const float*)d_in[2];
    const float* p1_b = (const float*)d_in[3];
    const float* p1_m = (const float*)d_in[4];
    const float* p1_v = (const float*)d_in[5];
    const float* p2_w = (const float*)d_in[6];
    const float* p2_g = (const float*)d_in[7];
    const float* p2_b = (const float*)d_in[8];
    const float* p2_m = (const float*)d_in[9];
    const float* p2_v = (const float*)d_in[10];
    const float* p_w  = (const float*)d_in[11];
    const float* p_g  = (const float*)d_in[12];
    const float* p_b  = (const float*)d_in[13];
    const float* p_m  = (const float*)d_in[14];
    const float* p_v  = (const float*)d_in[15];
    const float* c1_w = (const float*)d_in[16];
    const float* c1_g = (const float*)d_in[17];
    const float* c1_b = (const float*)d_in[18];
    const float* c1_m = (const float*)d_in[19];
    const float* c1_v = (const float*)d_in[20];
    const float* c2_w = (const float*)d_in[21];
    const float* c2_g = (const float*)d_in[22];
    const float* c2_b = (const float*)d_in[23];
    const float* c2_m = (const float*)d_in[24];
    const float* c2_v = (const float*)d_in[25];
    float* out = (float*)d_out;
    char* ws = (char*)d_ws;

    // layout (bytes), total 70,516,992 (<= proven-safe 70,778,880):
    //   Xc @0 (33,554,432) | Rc @33,554,432 (33,554,432)
    //   U @67,108,864 / V @67,895,296 (alias Aw1 @67,108,864, Aw2 @67,698,688)
    //   Aw5 @68,681,728 | Aw4 @69,861,376 | cmaxU @69,992,448 | rmaxU @70,254,592
    //   zbuf @70,516,736 (256)
    __hip_bfloat16* Xc   = (__hip_bfloat16*)ws;
    __hip_bfloat16* Rc   = (__hip_bfloat16*)(ws + 33554432);
    __hip_bfloat16* Ubuf = (__hip_bfloat16*)(ws + 67108864);
    __hip_bfloat16* Vbuf = (__hip_bfloat16*)(ws + 67895296);
    __hip_bfloat16* Aw1  = (__hip_bfloat16*)(ws + 67108864);
    __hip_bfloat16* Aw2  = (__hip_bfloat16*)(ws + 67698688);
    __hip_bfloat16* Aw5  = (__hip_bfloat16*)(ws + 68681728);
    __hip_bfloat16* Aw4  = (__hip_bfloat16*)(ws + 69861376);
    unsigned*       cmaxU = (unsigned*)(ws + 69992448);
    unsigned*       rmaxU = (unsigned*)(ws + 70254592);
    float*          zbuf  = (float*)(ws + 70516736);

    hipMemsetAsync(ws + 69992448, 0, 524544, stream);
    k_xprep<<<dim3(128, 4), 512, 0, stream>>>(x, Xc);
    k_wprep_all<<<dim3(640), 256, 0, stream>>>(
        p1_w, p2_w, c2_w, c1_w, Aw1, Aw2, Aw5, Aw4);

    // fused K1+K2: blockIdx.y = branch (0: colmax/Aw1, 1: rowmax/Aw2)
    k_conv3<1><<<dim3(64, 2, 4), 256, 0, stream>>>(
        Xc, Aw1, Aw2, zbuf,
        p1_g, p1_b, p1_m, p1_v, p2_g, p2_b, p2_m, p2_v,
        nullptr, cmaxU, rmaxU, CMID);

    k_uv<<<dim3(256, 4, 2), 128, 0, stream>>>(
        p_w, (const float*)cmaxU, (const float*)rmaxU, Ubuf, Vbuf);

    k_merge_mfma<<<dim3(128, 2, 4), 256, 0, stream>>>(
        Xc, Aw4, Ubuf, Vbuf, p_g, p_b, p_m, p_v,
        c1_g, c1_b, c1_m, c1_v, Rc);

    // K5: blockIdx.y = co-tile
    k_conv3<0><<<dim3(64, 2, 4), 256, 0, stream>>>(
        Rc, Aw5, nullptr, zbuf,
        c2_g, c2_b, c2_m, c2_v, nullptr, nullptr, nullptr, nullptr,
        out, nullptr, nullptr, CDIM);
}

// Round 7
// 390.552 us; speedup vs baseline: 16.0966x; 1.0055x over previous
//
#include <hip/hip_runtime.h>
#include <hip/hip_bf16.h>
#include <math.h>

// pool_cross on MI355X — round 7.
// (1) Conv LDS swizzle fixed: chunk slot ^= (row>>1)&3 -> 8-row-period bank
//     groups (round-5-style, which measured 0 conflicts) instead of round-6's
//     2-row period (8.06M conflicts/dispatch).
// (2) Merge v2: 256co x 128x per block (512 blocks = one 2-blk/CU round),
//     wave = 64co x 128x, proven 128B-row ^(row&7) swizzle, per-wave U stage.
// (3) memset folded into k_wprep_all: 6 dispatches total.
//
// pool algebra (verified): bottom(top(a)) = colmax bcast, right(left(a)) =
// rowmax bcast; merge conv input is rank-1 -> 1-D k_uv decomposition.
// Pool maxes via atomicMax on fp32 bits (valid: values >= 0 post-relu).

constexpr int NB   = 4;
constexpr int CDIM = 256;
constexpr int CMID = 128;
constexpr int HS   = 128;
constexpr int WS   = 128;
constexpr float EPS = 1e-5f;

typedef __bf16 bf16x8 __attribute__((ext_vector_type(8)));
typedef float  f32x4  __attribute__((ext_vector_type(4)));

#define AS1 __attribute__((address_space(1)))
#define AS3 __attribute__((address_space(3)))

__device__ __forceinline__ void load16_lds(const void* gsrc, void* ldst) {
    __builtin_amdgcn_global_load_lds((const AS1 unsigned int*)gsrc,
                                     (AS3 unsigned int*)ldst, 16, 0, 0);
}

// ---------------------------------------------------------------------------
// P0: x[b][ci][y][x] fp32 -> Xc[b][y][x][ci] bf16. Single pass, 512 threads.
__global__ __launch_bounds__(512) void k_xprep(const float* __restrict__ xin,
                                               __hip_bfloat16* __restrict__ Xc)
{
    const int y = blockIdx.x;
    const int b = blockIdx.y;
    const int t = threadIdx.x;
    __shared__ __hip_bfloat16 lds[128 * 264];   // [x][ci], ci-dim padded to 264
#pragma unroll
    for (int k = 0; k < 16; ++k) {
        int idx = t + k * 512;            // 0..8191
        int ci = idx >> 5, x4 = idx & 31;
        f32x4 v = *(const f32x4*)(xin + (((size_t)b * CDIM + ci) * HS + y) * WS + x4 * 4);
#pragma unroll
        for (int j = 0; j < 4; ++j)
            lds[(x4 * 4 + j) * 264 + ci] = __float2bfloat16(v[j]);
    }
    __syncthreads();
#pragma unroll
    for (int k = 0; k < 8; ++k) {
        int i = t + k * 512;              // 0..4095 chunks of 16B
        int x = i >> 5, c8 = i & 31;
        bf16x8 vv = *(const bf16x8*)(lds + x * 264 + c8 * 8);
        *(bf16x8*)(Xc + ((size_t)(b * 128 + y) * 128 + x) * 256 + c8 * 8) = vv;
    }
}

// ---------------------------------------------------------------------------
// All weight preps + zero-fill in one kernel.
// bid 0..127: Aw1; 128..255: Aw2; 256..511: Aw5; 512..639: Aw4 (1x1);
// bid 640..767: zero 4KB each of the cmax|rmax|zbuf region; 768: tail 256B.
__global__ __launch_bounds__(256) void k_wprep_all(
    const float* __restrict__ p1w, const float* __restrict__ p2w,
    const float* __restrict__ c2w, const float* __restrict__ c1w,
    __hip_bfloat16* __restrict__ Aw1, __hip_bfloat16* __restrict__ Aw2,
    __hip_bfloat16* __restrict__ Aw5, __hip_bfloat16* __restrict__ Aw4,
    f32x4* __restrict__ zdst)
{
    const int bid = blockIdx.x;
    const int t   = threadIdx.x;
    if (bid < 512) {
        const float* W; __hip_bfloat16* A; int co;
        if (bid < 128)      { W = p1w; A = Aw1; co = bid; }
        else if (bid < 256) { W = p2w; A = Aw2; co = bid - 128; }
        else                { W = c2w; A = Aw5; co = bid - 256; }
#pragma unroll
        for (int tap = 0; tap < 9; ++tap)
            A[(size_t)co * 2304 + tap * 256 + t] =
                __float2bfloat16(W[((size_t)co * CDIM + t) * 9 + tap]);
    } else if (bid < 640) {
        int base = (bid - 512) * 512 + t;
        Aw4[base]       = __float2bfloat16(c1w[base]);
        Aw4[base + 256] = __float2bfloat16(c1w[base + 256]);
    } else if (bid < 768) {
        zdst[(size_t)(bid - 640) * 256 + t] = (f32x4){0.f, 0.f, 0.f, 0.f};
    } else {
        if (t < 16) zdst[32768 + t] = (f32x4){0.f, 0.f, 0.f, 0.f};
    }
}

// ---------------------------------------------------------------------------
// Conv3x3 implicit GEMM v2 (2 y-rows x 128co x 128x), 32-ci chunks, 64B LDS
// rows with slot = c ^ ((row>>1)&3) swizzle (8-row bank-group period).
// MODE 0: plain fp32 NCHW store (K5). MODE 1: fused branches (K1+K2):
// blockIdx.y==0 -> colmax atomics, ==1 -> rowmax atomics (LDS pre-reduce).
template<int MODE>
__global__ __launch_bounds__(256, 2) void k_conv3(
    const __hip_bfloat16* __restrict__ Xc,
    const __hip_bfloat16* __restrict__ AwA, const __hip_bfloat16* __restrict__ AwB,
    const float* __restrict__ zbuf,
    const float* __restrict__ g1, const float* __restrict__ b1,
    const float* __restrict__ m1, const float* __restrict__ v1,
    const float* __restrict__ g2, const float* __restrict__ b2,
    const float* __restrict__ m2, const float* __restrict__ v2,
    float* __restrict__ out0, unsigned* __restrict__ cmax,
    unsigned* __restrict__ rmax, int CO)
{
    const int y0     = blockIdx.x * 2;
    const int branch = blockIdx.y;              // MODE1: branch; MODE0: co-tile
    const int b      = blockIdx.z;
    const int co0    = (MODE == 0) ? branch * 128 : 0;

    const __hip_bfloat16* Aw = (MODE == 1 && branch) ? AwB : AwA;
    const float* gg  = (MODE == 1 && branch) ? g2 : g1;
    const float* bbp = (MODE == 1 && branch) ? b2 : b1;
    const float* mmp = (MODE == 1 && branch) ? m2 : m1;
    const float* vvp = (MODE == 1 && branch) ? v2 : v1;

    __shared__ __hip_bfloat16 smem[644 * 32];   // 644 rows x 64 B = 41,216 B
    __shared__ float s_sc[128], s_sh[128];
    __shared__ unsigned s_red[2][128];
    char* smb = (char*)smem;

    const int t    = threadIdx.x;
    const int lane = t & 63;
    const int w    = t >> 6;
    const int ml   = lane & 15;
    const int q    = lane >> 4;
    const int mbase = (w >> 1) * 64;
    const int nbase = (w & 1) * 64;

    if (t < 128) {
        int co = co0 + t;
        float iv = rsqrtf(vvp[co] + EPS);
        float sc = gg[co] * iv;
        s_sc[t] = sc;
        s_sh[t] = bbp[co] - mmp[co] * sc;
        if (MODE == 1) { s_red[0][t] = 0u; s_red[1][t] = 0u; }
    }

    f32x4 acc[2][4][4];
#pragma unroll
    for (int yy = 0; yy < 2; ++yy)
#pragma unroll
        for (int mt = 0; mt < 4; ++mt)
#pragma unroll
            for (int nt = 0; nt < 4; ++nt)
                acc[yy][mt][nt] = (f32x4){0.f, 0.f, 0.f, 0.f};

    const __hip_bfloat16* bbase = Xc + (size_t)(b * 128) * 128 * 256;

#pragma unroll 1
    for (int ky = 0; ky < 3; ++ky) {
        const int yd0 = y0 + ky - 1;
        const __hip_bfloat16* arow = Aw + (size_t)co0 * 2304 + (3 * ky) * 256;
#pragma unroll 1
        for (int cih = 0; cih < 8; ++cih) {
            const int cb = cih * 32;
            // stage 2576 x 16B; slot sl holds logical chunk sl^((row>>1)&3)
#pragma unroll
            for (int p = 0; p < 11; ++p) {
                int i = t + p * 256;
                if (i < 2576) {
                    int row = i >> 2, sl = i & 3;
                    int c = sl ^ ((row >> 1) & 3);
                    const __hip_bfloat16* src;
                    if (row < 384) {
                        int j = row >> 7, col = row & 127;
                        src = arow + (size_t)col * 2304 + j * 256 + cb + c * 8;
                    } else {
                        int rbi = row - 384;
                        int yy  = rbi >= 130;
                        int xi  = rbi - 130 * yy;
                        int gy  = yd0 + yy, gx = xi - 1;
                        src = ((unsigned)gy < 128u && (unsigned)gx < 128u)
                            ? bbase + ((size_t)(gy * 128 + gx)) * 256 + cb + c * 8
                            : (const __hip_bfloat16*)((const char*)zbuf + c * 16);
                    }
                    load16_lds(src, smb + (size_t)i * 16);
                }
            }
            __syncthreads();
            // 3 kx, A-frag shared across 2 y rows
#pragma unroll
            for (int j = 0; j < 3; ++j) {
                bf16x8 af[4];
#pragma unroll
                for (int mt = 0; mt < 4; ++mt) {
                    const int ra = j * 128 + mbase + mt * 16 + ml;
                    const int sa = q ^ ((ra >> 1) & 3);
                    af[mt] = *(const bf16x8*)(smb + (size_t)ra * 64 + sa * 16);
                }
#pragma unroll
                for (int yy = 0; yy < 2; ++yy) {
                    bf16x8 bfv[4];
#pragma unroll
                    for (int nt = 0; nt < 4; ++nt) {
                        const int rb = 384 + yy * 130 + nbase + nt * 16 + ml + j;
                        const int sb = q ^ ((rb >> 1) & 3);
                        bfv[nt] = *(const bf16x8*)(smb + (size_t)rb * 64 + sb * 16);
                    }
#pragma unroll
                    for (int mt = 0; mt < 4; ++mt)
#pragma unroll
                        for (int nt = 0; nt < 4; ++nt)
                            acc[yy][mt][nt] = __builtin_amdgcn_mfma_f32_16x16x32_bf16(
                                af[mt], bfv[nt], acc[yy][mt][nt], 0, 0, 0);
                }
            }
            __syncthreads();
        }
    }

    // epilogue. C/D: col(x)=ml, row(co)=q*4+r.
#pragma unroll
    for (int mt = 0; mt < 4; ++mt) {
#pragma unroll
        for (int r = 0; r < 4; ++r) {
            const int col = mbase + mt * 16 + q * 4 + r;
            const float sc = s_sc[col], sh = s_sh[col];
            const int co = co0 + col;
            unsigned rmx0 = 0u, rmx1 = 0u;
#pragma unroll
            for (int nt = 0; nt < 4; ++nt) {
                float va = fmaxf(acc[0][mt][nt][r] * sc + sh, 0.f);
                float vb = fmaxf(acc[1][mt][nt][r] * sc + sh, 0.f);
                const int x = nbase + nt * 16 + ml;
                if (MODE == 0) {
                    out0[(((size_t)b * CO + co) * HS + y0)     * WS + x] = va;
                    out0[(((size_t)b * CO + co) * HS + y0 + 1) * WS + x] = vb;
                } else if (branch == 0) {
                    atomicMax(cmax + ((size_t)(b * 128 + co)) * 128 + x,
                              __float_as_uint(fmaxf(va, vb)));
                } else {
                    rmx0 = max(rmx0, __float_as_uint(va));
                    rmx1 = max(rmx1, __float_as_uint(vb));
                }
            }
            if (MODE == 1 && branch == 1) {
                atomicMax(&s_red[0][col], rmx0);
                atomicMax(&s_red[1][col], rmx1);
            }
        }
    }
    if (MODE == 1 && branch == 1) {
        __syncthreads();
        if (t < 128) {
            atomicMax(rmax + ((size_t)(b * 128 + t)) * 128 + y0,     s_red[0][t]);
            atomicMax(rmax + ((size_t)(b * 128 + t)) * 128 + y0 + 1, s_red[1][t]);
        }
    }
}

// ---------------------------------------------------------------------------
// K3: 1-D decomposition of the merge conv -> U,V (bf16 out).
__global__ __launch_bounds__(128) void k_uv(
    const float* __restrict__ pw, const float* __restrict__ cm,
    const float* __restrict__ rm,
    __hip_bfloat16* __restrict__ U, __hip_bfloat16* __restrict__ V)
{
    const int co   = blockIdx.x;
    const int b    = blockIdx.y;
    const int mode = blockIdx.z;
    const int p    = threadIdx.x;
    float acc0 = 0.f, acc1 = 0.f, acc2 = 0.f;
    const float* base = (mode == 0) ? cm : rm;
    for (int ci = 0; ci < CMID; ++ci) {
        const float* w9 = pw + (co * CMID + ci) * 9;
        float s0[3], s1[3], s2[3];
        if (mode == 0) {
#pragma unroll
            for (int k = 0; k < 3; ++k) {
                float a = w9[k], qq = w9[3 + k], r = w9[6 + k];
                s0[k] = qq + r; s1[k] = a + qq + r; s2[k] = a + qq;
            }
        } else {
#pragma unroll
            for (int k = 0; k < 3; ++k) {
                float a = w9[k*3 + 0], qq = w9[k*3 + 1], r = w9[k*3 + 2];
                s0[k] = qq + r; s1[k] = a + qq + r; s2[k] = a + qq;
            }
        }
        const float* v = base + (b * CMID + ci) * 128;
#pragma unroll
        for (int k = 0; k < 3; ++k) {
            int pos = p + k - 1;
            if ((unsigned)pos < 128u) {
                float vv = v[pos];
                acc0 += s0[k] * vv; acc1 += s1[k] * vv; acc2 += s2[k] * vv;
            }
        }
    }
    __hip_bfloat16* dst = (mode == 0) ? U : V;
    dst[((0 * NB + b) * CDIM + co) * 128 + p] = __float2bfloat16(acc0);
    dst[((1 * NB + b) * CDIM + co) * 128 + p] = __float2bfloat16(acc1);
    dst[((2 * NB + b) * CDIM + co) * 128 + p] = __float2bfloat16(acc2);
}

// ---------------------------------------------------------------------------
// K4 v2: merge as MFMA GEMM, 256co x 128x per block (one y row), 4 waves,
// wave = 64co x 128x (acc 4x8). 128B LDS rows, slot = c ^ (row&7) swizzle.
// Rc[b][y][x][co] = relu(psc*(U+V)+psh + csc*conv1x1+csh), bf16.
__global__ __launch_bounds__(256, 2) void k_merge_mfma(
    const __hip_bfloat16* __restrict__ Xc, const __hip_bfloat16* __restrict__ Aw4,
    const __hip_bfloat16* __restrict__ U, const __hip_bfloat16* __restrict__ V,
    const float* __restrict__ pg, const float* __restrict__ pb,
    const float* __restrict__ pm, const float* __restrict__ pv,
    const float* __restrict__ cg, const float* __restrict__ cb,
    const float* __restrict__ cmn, const float* __restrict__ cv,
    __hip_bfloat16* __restrict__ Rc)
{
    const int y = blockIdx.x;
    const int b = blockIdx.y;
    __shared__ __hip_bfloat16 smem[32768];   // 64 KB: GEMM staging, then U tiles
    __shared__ float s_psc[256], s_psh[256], s_csc[256], s_csh[256];
    __shared__ float s_v0[256], s_vm[256], s_v1[256];
    char* smb = (char*)smem;
    const int t = threadIdx.x, lane = t & 63, w = t >> 6;
    const int ml = lane & 15, q = lane >> 4;
    const int mbase = w * 64;                // wave's co offset
    const int yc = (y == 0) ? 0 : ((y == HS - 1) ? 2 : 1);

    {   // 256 threads cover 256 co
        int co = t;
        float iv = rsqrtf(pv[co] + EPS);
        float psc = pg[co] * iv;
        s_psc[co] = psc;
        s_psh[co] = pb[co] - pm[co] * psc;
        float iv2 = rsqrtf(cv[co] + EPS);
        float csc = cg[co] * iv2;
        s_csc[co] = csc;
        s_csh[co] = cb[co] - cmn[co] * csc;
        const size_t vb = ((size_t)b * CDIM + co) * 128 + y;
        const size_t cstr = (size_t)NB * CDIM * 128;
        s_v0[co] = __bfloat162float(V[vb]);
        s_vm[co] = __bfloat162float(V[cstr + vb]);
        s_v1[co] = __bfloat162float(V[2 * cstr + vb]);
    }

    f32x4 acc[4][8];
#pragma unroll
    for (int mt = 0; mt < 4; ++mt)
#pragma unroll
        for (int nt = 0; nt < 8; ++nt)
            acc[mt][nt] = (f32x4){0.f, 0.f, 0.f, 0.f};

    const __hip_bfloat16* brow = Xc + (size_t)(b * 128 + y) * 128 * 256;
#pragma unroll 1
    for (int ks = 0; ks < 4; ++ks) {
        // stage 384 rows x 128B: A rows 0..255 (co), B rows 256..383 (x)
#pragma unroll
        for (int p = 0; p < 12; ++p) {
            int i   = t + p * 256;           // 0..3071
            int row = i >> 3, sl = i & 7;
            int c   = sl ^ (row & 7);
            const __hip_bfloat16* src = (row < 256)
                ? Aw4 + (size_t)row * 256 + ks * 64 + c * 8
                : brow + (size_t)(row - 256) * 256 + ks * 64 + c * 8;
            load16_lds(src, smb + (size_t)i * 16);
        }
        __syncthreads();
#pragma unroll
        for (int s = 0; s < 2; ++s) {
            bf16x8 af[4], bfv[8];
#pragma unroll
            for (int mt = 0; mt < 4; ++mt) {
                const int ra = mbase + mt * 16 + ml;
                const int coff = ((s * 4 + q) ^ (ra & 7)) * 16;
                af[mt] = *(const bf16x8*)(smb + (size_t)ra * 128 + coff);
            }
#pragma unroll
            for (int nt = 0; nt < 8; ++nt) {
                const int rb = 256 + nt * 16 + ml;
                const int coff = ((s * 4 + q) ^ (rb & 7)) * 16;
                bfv[nt] = *(const bf16x8*)(smb + (size_t)rb * 128 + coff);
            }
#pragma unroll
            for (int mt = 0; mt < 4; ++mt)
#pragma unroll
                for (int nt = 0; nt < 8; ++nt)
                    acc[mt][nt] = __builtin_amdgcn_mfma_f32_16x16x32_bf16(
                        af[mt], bfv[nt], acc[mt][nt], 0, 0, 0);
        }
        __syncthreads();
    }

    // per-wave U stage: 64co x 128x bf16 = 16 KB at wave offset (contiguous)
    const __hip_bfloat16* Ub = U + ((size_t)(yc * NB + b) * CDIM + mbase) * 128;
#pragma unroll
    for (int k = 0; k < 16; ++k) {
        int i = lane + k * 64;
        load16_lds(Ub + (size_t)i * 8, smb + (size_t)w * 16384 + (size_t)i * 16);
    }
    __syncthreads();
    const __hip_bfloat16* ulds = smem + w * 8192;

#pragma unroll
    for (int mt = 0; mt < 4; ++mt) {
#pragma unroll
        for (int nt = 0; nt < 8; ++nt) {
            const int x = nt * 16 + ml;
            unsigned long long pk = 0;
#pragma unroll
            for (int r = 0; r < 4; ++r) {
                const int cl = mt * 16 + q * 4 + r;       // local co in wave
                const int co = mbase + cl;
                float u  = __bfloat162float(ulds[cl * 128 + x]);
                float vt = (x == 0) ? s_v0[co] : ((x == WS - 1) ? s_v1[co] : s_vm[co]);
                float val = fmaxf((u + vt) * s_psc[co] + s_psh[co]
                                  + acc[mt][nt][r] * s_csc[co] + s_csh[co], 0.f);
                __hip_bfloat16 hb = __float2bfloat16(val);
                unsigned short bits;
                __builtin_memcpy(&bits, &hb, 2);
                pk |= (unsigned long long)bits << (16 * r);
            }
            *(unsigned long long*)((char*)Rc +
                ((size_t)((b * 128 + y) * 128 + x) * 256 + mbase + mt * 16 + q * 4) * 2) = pk;
        }
    }
}

// ---------------------------------------------------------------------------
extern "C" void kernel_launch(void* const* d_in, const int* in_sizes, int n_in,
                              void* d_out, int out_size, void* d_ws, size_t ws_size,
                              hipStream_t stream)
{
    (void)in_sizes; (void)n_in; (void)out_size; (void)ws_size;
    const float* x    = (const float*)d_in[0];
    const float* p1_w = (const float*)d_in[1];
    const float* p1_g = (const float*)d_in[2];
    const float* p1_b = (const float*)d_in[3];
    const float* p1_m = (const float*)d_in[4];
    const float* p1_v = (const float*)d_in[5];
    const float* p2_w = (const float*)d_in[6];
    const float* p2_g = (const float*)d_in[7];
    const float* p2_b = (const float*)d_in[8];
    const float* p2_m = (const float*)d_in[9];
    const float* p2_v = (const float*)d_in[10];
    const float* p_w  = (const float*)d_in[11];
    const float* p_g  = (const float*)d_in[12];
    const float* p_b  = (const float*)d_in[13];
    const float* p_m  = (const float*)d_in[14];
    const float* p_v  = (const float*)d_in[15];
    const float* c1_w = (const float*)d_in[16];
    const float* c1_g = (const float*)d_in[17];
    const float* c1_b = (const float*)d_in[18];
    const float* c1_m = (const float*)d_in[19];
    const float* c1_v = (const float*)d_in[20];
    const float* c2_w = (const float*)d_in[21];
    const float* c2_g = (const float*)d_in[22];
    const float* c2_b = (const float*)d_in[23];
    const float* c2_m = (const float*)d_in[24];
    const float* c2_v = (const float*)d_in[25];
    float* out = (float*)d_out;
    char* ws = (char*)d_ws;

    // layout (bytes), total 70,516,992 (<= proven-safe 70,778,880):
    //   Xc @0 (33,554,432) | Rc @33,554,432 (33,554,432)
    //   U @67,108,864 / V @67,895,296 (alias Aw1 @67,108,864, Aw2 @67,698,688)
    //   Aw5 @68,681,728 | Aw4 @69,861,376
    //   zero region @69,992,448 (524,544): cmaxU | rmaxU @70,254,592 | zbuf @70,516,736
    __hip_bfloat16* Xc   = (__hip_bfloat16*)ws;
    __hip_bfloat16* Rc   = (__hip_bfloat16*)(ws + 33554432);
    __hip_bfloat16* Ubuf = (__hip_bfloat16*)(ws + 67108864);
    __hip_bfloat16* Vbuf = (__hip_bfloat16*)(ws + 67895296);
    __hip_bfloat16* Aw1  = (__hip_bfloat16*)(ws + 67108864);
    __hip_bfloat16* Aw2  = (__hip_bfloat16*)(ws + 67698688);
    __hip_bfloat16* Aw5  = (__hip_bfloat16*)(ws + 68681728);
    __hip_bfloat16* Aw4  = (__hip_bfloat16*)(ws + 69861376);
    unsigned*       cmaxU = (unsigned*)(ws + 69992448);
    unsigned*       rmaxU = (unsigned*)(ws + 70254592);
    float*          zbuf  = (float*)(ws + 70516736);

    k_wprep_all<<<dim3(769), 256, 0, stream>>>(
        p1_w, p2_w, c2_w, c1_w, Aw1, Aw2, Aw5, Aw4, (f32x4*)(ws + 69992448));
    k_xprep<<<dim3(128, 4), 512, 0, stream>>>(x, Xc);

    // fused K1+K2: blockIdx.y = branch (0: colmax/Aw1, 1: rowmax/Aw2)
    k_conv3<1><<<dim3(64, 2, 4), 256, 0, stream>>>(
        Xc, Aw1, Aw2, zbuf,
        p1_g, p1_b, p1_m, p1_v, p2_g, p2_b, p2_m, p2_v,
        nullptr, cmaxU, rmaxU, CMID);

    k_uv<<<dim3(256, 4, 2), 128, 0, stream>>>(
        p_w, (const float*)cmaxU, (const float*)rmaxU, Ubuf, Vbuf);

    k_merge_mfma<<<dim3(128, 4), 256, 0, stream>>>(
        Xc, Aw4, Ubuf, Vbuf, p_g, p_b, p_m, p_v,
        c1_g, c1_b, c1_m, c1_v, Rc);

    // K5: blockIdx.y = co-tile
    k_conv3<0><<<dim3(64, 2, 4), 256, 0, stream>>>(
        Rc, Aw5, nullptr, zbuf,
        c2_g, c2_b, c2_m, c2_v, nullptr, nullptr, nullptr, nullptr,
        out, nullptr, nullptr, CDIM);
}